// Round 10
// baseline (526.228 us; speedup 1.0000x reference)
//
#include <hip/hip_runtime.h>
#include <hip/hip_bf16.h>
#include <hip/hip_fp16.h>

#define NN 100000      // nodes
#define EE 1600000     // edges
#define GG 1024        // graphs
#define NF 9
#define VV 128
#define HH 128
#define LL 3
#define OUTD 10
#define BN_EPS 1e-5f
#define NB_SCAN 98     // ceil(NN/1024)
#define NBUCK 196      // ceil(NN/512) buckets of 512 nodes
#define BCAP 12288     // bucket capacity (avg fill 8192)
#define CHUNK 4096     // edges per split block

typedef __attribute__((ext_vector_type(8))) short short8;   // 8 bf16 = 4 VGPRs
typedef __attribute__((ext_vector_type(4))) float f32x4;

__device__ inline unsigned short f2bf(float x) {          // RNE f32 -> bf16 bits
    unsigned u = __float_as_uint(x);
    unsigned r = (u + 0x7fffu + ((u >> 16) & 1u)) >> 16;
    return (unsigned short)r;
}
__device__ inline float bf2f(unsigned short b) { return __uint_as_float(((unsigned)b) << 16); }

// ---------------- Two-level CSR build ----------------
__global__ __launch_bounds__(256) void split_kernel(const int* __restrict__ src,
                                                    const int* __restrict__ dst,
                                                    int* __restrict__ bcur,
                                                    int* __restrict__ bucket_edges) {
    __shared__ int lcnt[256], loff[256], lcur[256], gbase[256], sh[256];
    __shared__ int stage[CHUNK];
    __shared__ unsigned char stageb[CHUNK];
    int tid = threadIdx.x;
    int cs = blockIdx.x * CHUNK;
    int n = min(CHUNK, EE - cs);
    lcnt[tid] = 0;
    __syncthreads();
    for (int i = tid; i < n; i += 256)
        atomicAdd(&lcnt[dst[cs + i] >> 9], 1);
    __syncthreads();
    int val = lcnt[tid];
    sh[tid] = val; __syncthreads();
    for (int d = 1; d < 256; d <<= 1) {
        int t = (tid >= d) ? sh[tid - d] : 0;
        __syncthreads();
        sh[tid] += t;
        __syncthreads();
    }
    loff[tid] = sh[tid] - val;
    lcur[tid] = sh[tid] - val;
    __syncthreads();
    for (int i = tid; i < n; i += 256) {
        int d = dst[cs + i], s = src[cs + i];
        int b = d >> 9;
        int p = atomicAdd(&lcur[b], 1);
        stage[p] = (s << 9) | (d & 511);
        stageb[p] = (unsigned char)b;
    }
    if (val > 0) gbase[tid] = atomicAdd(&bcur[tid], val);
    __syncthreads();
    for (int i = tid; i < n; i += 256) {
        int b = stageb[i];
        bucket_edges[(size_t)b * BCAP + gbase[b] + (i - loff[b])] = stage[i];
    }
}

__global__ __launch_bounds__(256) void bhist_kernel(const int* __restrict__ bcur,
                                                    const int* __restrict__ bucket_edges,
                                                    int* __restrict__ cnt) {
    __shared__ int lc[512];
    int b = blockIdx.x, tid = threadIdx.x;
    lc[tid] = 0; lc[tid + 256] = 0;
    __syncthreads();
    int n = bcur[b];
    const int* be = bucket_edges + (size_t)b * BCAP;
    for (int i = tid; i < n; i += 256) atomicAdd(&lc[be[i] & 511], 1);
    __syncthreads();
    int node = b * 512 + tid;
    if (node < NN) cnt[node] = lc[tid];
    node += 256;
    if (node < NN) cnt[node] = lc[tid + 256];
}

__global__ void scanA_kernel(const int* __restrict__ cnt, int* __restrict__ bsum,
                             float* __restrict__ dinv) {
    __shared__ int sh[256];
    int tid = threadIdx.x;
    int base = blockIdx.x * 1024 + tid * 4;
    int s = 0;
#pragma unroll
    for (int i = 0; i < 4; ++i) {
        int idx = base + i;
        if (idx < NN) {
            int c = cnt[idx];
            s += c;
            dinv[idx] = rsqrtf(1.0f + (float)c);
        }
    }
    sh[tid] = s; __syncthreads();
    for (int d = 128; d > 0; d >>= 1) { if (tid < d) sh[tid] += sh[tid + d]; __syncthreads(); }
    if (tid == 0) bsum[blockIdx.x] = sh[0];
}

__global__ void scanB_kernel(int* __restrict__ bsum) {
    __shared__ int sh[128];
    int tid = threadIdx.x;
    int v = (tid < NB_SCAN) ? bsum[tid] : 0;
    sh[tid] = v; __syncthreads();
    for (int d = 1; d < 128; d <<= 1) {
        int t = (tid >= d) ? sh[tid - d] : 0;
        __syncthreads();
        sh[tid] += t;
        __syncthreads();
    }
    if (tid < NB_SCAN) bsum[tid] = sh[tid] - v;
}

__global__ void scanC_kernel(const int* __restrict__ cnt, const int* __restrict__ bsum,
                             int* __restrict__ row_ptr) {
    __shared__ int sh[256];
    int tid = threadIdx.x;
    int base = blockIdx.x * 1024 + tid * 4;
    int v[4];
#pragma unroll
    for (int i = 0; i < 4; ++i) { int idx = base + i; v[i] = (idx < NN) ? cnt[idx] : 0; }
    int tsum = v[0] + v[1] + v[2] + v[3];
    sh[tid] = tsum; __syncthreads();
    for (int d = 1; d < 256; d <<= 1) {
        int t = (tid >= d) ? sh[tid - d] : 0;
        __syncthreads();
        sh[tid] += t;
        __syncthreads();
    }
    int excl = sh[tid] - tsum + bsum[blockIdx.x];
#pragma unroll
    for (int i = 0; i < 4; ++i) {
        int idx = base + i;
        if (idx < NN) row_ptr[idx] = excl;
        excl += v[i];
    }
    if (blockIdx.x == 0 && tid == 0) row_ptr[NN] = EE;
}

__global__ __launch_bounds__(256) void cscatter_kernel(const int* __restrict__ bcur,
                                                       const int* __restrict__ bucket_edges,
                                                       const int* __restrict__ row_ptr,
                                                       const float* __restrict__ dinv,
                                                       int2* __restrict__ col) {
    __shared__ int lcur[512];
    int b = blockIdx.x, tid = threadIdx.x;
    int node0 = b * 512;
#pragma unroll
    for (int k = 0; k < 2; ++k) {
        int j = tid + k * 256;
        int node = node0 + j;
        if (node < NN) lcur[j] = row_ptr[node];
    }
    __syncthreads();
    int n = bcur[b];
    const int* be = bucket_edges + (size_t)b * BCAP;
    for (int i = tid; i < n; i += 256) {
        int w = be[i];
        int j = w & 511;
        int s = (int)((unsigned)w >> 9);
        int p = atomicAdd(&lcur[j], 1);
        float nm = dinv[s] * dinv[node0 + j];
        col[p] = make_int2(s, __float_as_int(nm));
    }
}

// ---------------- W^T hi/lo conversion ----------------
__global__ void wconv_kernel(const float* __restrict__ Ws,
                             unsigned short* __restrict__ WThi,
                             unsigned short* __restrict__ WTlo) {
    int id = blockIdx.x * 256 + threadIdx.x;
    if (id >= LL * HH * HH) return;
    int layer = id >> 14;
    int rem = id & (HH * HH - 1);
    int k = rem >> 7, n = rem & 127;
    float w = Ws[id];
    unsigned short hi = f2bf(w);
    float lo = w - bf2f(hi);
    WThi[(size_t)layer * HH * HH + n * HH + k] = hi;   // transposed: [n][k]
    WTlo[(size_t)layer * HH * HH + n * HH + k] = f2bf(lo);
}

// ---------------- Fused: atom encoder -> LDS -> MFMA @ W0 -> hw ----------------
// Block = 32 nodes. Phase 1: thread = (node, 16-ch segment), sums 9 emb rows
// (emb 590 KB, L2-resident), writes bf16 hi/lo to LDS. Phase 2: MFMA tail.
__global__ __launch_bounds__(256) void enc_mm_kernel(const int* __restrict__ x,
        const float* __restrict__ emb,
        const unsigned short* __restrict__ WThi, const unsigned short* __restrict__ WTlo,
        __half* __restrict__ hw_out) {
    __shared__ __align__(16) unsigned short lh[32][136];
    __shared__ __align__(16) unsigned short ll[32][136];
    int tid = threadIdx.x;
    int nloc = tid >> 3;           // 0..31
    int seg = tid & 7;             // 16-ch segment
    int nodebase = blockIdx.x * 32;
    int n = nodebase + nloc;
    float s[16];
#pragma unroll
    for (int i = 0; i < 16; ++i) s[i] = 0.f;
#pragma unroll
    for (int f = 0; f < NF; ++f) {
        int idx = x[n * NF + f];
        const float4* ep = (const float4*)(emb + ((size_t)(f * VV + idx)) * HH + seg * 16);
#pragma unroll
        for (int q = 0; q < 4; ++q) {
            float4 e = ep[q];
            s[q * 4 + 0] += e.x; s[q * 4 + 1] += e.y;
            s[q * 4 + 2] += e.z; s[q * 4 + 3] += e.w;
        }
    }
#pragma unroll
    for (int q = 0; q < 4; ++q) {
        ushort4 oh, ol;
        oh.x = f2bf(s[q * 4 + 0]); ol.x = f2bf(s[q * 4 + 0] - bf2f(oh.x));
        oh.y = f2bf(s[q * 4 + 1]); ol.y = f2bf(s[q * 4 + 1] - bf2f(oh.y));
        oh.z = f2bf(s[q * 4 + 2]); ol.z = f2bf(s[q * 4 + 2] - bf2f(oh.z));
        oh.w = f2bf(s[q * 4 + 3]); ol.w = f2bf(s[q * 4 + 3] - bf2f(oh.w));
        *(ushort4*)&lh[nloc][seg * 16 + q * 4] = oh;
        *(ushort4*)&ll[nloc][seg * 16 + q * 4] = ol;
    }
    __syncthreads();
    int wave = tid >> 6, lane = tid & 63;
    int quad = lane >> 4, m = lane & 15;
    f32x4 acc[2][2] = {};
    int kq = quad * 8;
#pragma unroll
    for (int t = 0; t < 4; ++t) {
        int k0 = t * 32 + kq;
        short8 a0h = *(const short8*)&lh[m][k0];
        short8 a0l = *(const short8*)&ll[m][k0];
        short8 a1h = *(const short8*)&lh[16 + m][k0];
        short8 a1l = *(const short8*)&ll[16 + m][k0];
#pragma unroll
        for (int c = 0; c < 2; ++c) {
            int ct = wave * 2 + c;
            short8 bh = *(const short8*)(WThi + (size_t)(ct * 16 + m) * HH + k0);
            short8 bl = *(const short8*)(WTlo + (size_t)(ct * 16 + m) * HH + k0);
            acc[0][c] = __builtin_amdgcn_mfma_f32_16x16x32_bf16(a0h, bh, acc[0][c], 0, 0, 0);
            acc[0][c] = __builtin_amdgcn_mfma_f32_16x16x32_bf16(a0l, bh, acc[0][c], 0, 0, 0);
            acc[0][c] = __builtin_amdgcn_mfma_f32_16x16x32_bf16(a0h, bl, acc[0][c], 0, 0, 0);
            acc[1][c] = __builtin_amdgcn_mfma_f32_16x16x32_bf16(a1h, bh, acc[1][c], 0, 0, 0);
            acc[1][c] = __builtin_amdgcn_mfma_f32_16x16x32_bf16(a1l, bh, acc[1][c], 0, 0, 0);
            acc[1][c] = __builtin_amdgcn_mfma_f32_16x16x32_bf16(a1h, bl, acc[1][c], 0, 0, 0);
        }
    }
#pragma unroll
    for (int c = 0; c < 2; ++c) {
        int colx = (wave * 2 + c) * 16 + m;
#pragma unroll
        for (int rt = 0; rt < 2; ++rt) {
            int r0 = nodebase + rt * 16 + quad * 4;
#pragma unroll
            for (int reg = 0; reg < 4; ++reg)
                hw_out[(size_t)(r0 + reg) * HH + colx] = __float2half(acc[rt][c][reg]);
        }
    }
}

// ---------------- Fused: CSR aggregate + bias + BN + ReLU -> LDS -> MFMA @ Wnext ----------------
// Gather loop: 16 edges/iteration (4 per quarter-group, 4 independent acc sets).
__global__ __launch_bounds__(256) void agg_mm_kernel(const __half* __restrict__ hw_in,
    const int* __restrict__ row_ptr, const int2* __restrict__ col,
    const float* __restrict__ dinv,
    const float* __restrict__ bias, const float* __restrict__ gamma,
    const float* __restrict__ beta, const float* __restrict__ rmean,
    const float* __restrict__ rvar,
    const unsigned short* __restrict__ WThi, const unsigned short* __restrict__ WTlo,
    __half* __restrict__ hw_out) {
    __shared__ __align__(16) unsigned short lh[32][136];
    __shared__ __align__(16) unsigned short ll[32][136];
    int wave = threadIdx.x >> 6;
    int lane = threadIdx.x & 63;
    int grp = lane >> 4;             // 0..3
    int c4 = lane & 15;
    int nodebase = blockIdx.x * 32;
    const uint4* hw4 = (const uint4*)hw_in;

    for (int nn = 0; nn < 8; ++nn) {
        int v = nodebase + wave * 8 + nn;
        int start = row_ptr[v], end = row_ptr[v + 1];
        float a[8] = {}, b[8] = {}, cA[8] = {}, dA[8] = {};
        for (int j0 = start; j0 < end; j0 += 64) {
            int jj = j0 + lane;
            int sp = 0; float np = 0.f;
            if (jj < end) {
                unsigned long long w = __builtin_nontemporal_load((const unsigned long long*)&col[jj]);
                sp = (int)(unsigned)(w & 0xffffffffu);
                np = __int_as_float((int)(unsigned)(w >> 32));
            }
            int rem = min(64, end - j0);
            int nb = (rem + 15) >> 4;
            for (int it = 0; it < nb; ++it) {
                int e0 = it * 16 + grp;
                int s0 = __shfl(sp, e0),      s1 = __shfl(sp, e0 + 4);
                int s2 = __shfl(sp, e0 + 8),  s3 = __shfl(sp, e0 + 12);
                float n0 = __shfl(np, e0),     n1 = __shfl(np, e0 + 4);
                float n2 = __shfl(np, e0 + 8), n3 = __shfl(np, e0 + 12);
                uint4 r0 = hw4[(size_t)s0 * 16 + c4];
                uint4 r1 = hw4[(size_t)s1 * 16 + c4];
                uint4 r2 = hw4[(size_t)s2 * 16 + c4];
                uint4 r3 = hw4[(size_t)s3 * 16 + c4];
                float2 f;
                f = __half22float2(*(const __half2*)&r0.x); a[0] = fmaf(n0, f.x, a[0]); a[1] = fmaf(n0, f.y, a[1]);
                f = __half22float2(*(const __half2*)&r0.y); a[2] = fmaf(n0, f.x, a[2]); a[3] = fmaf(n0, f.y, a[3]);
                f = __half22float2(*(const __half2*)&r0.z); a[4] = fmaf(n0, f.x, a[4]); a[5] = fmaf(n0, f.y, a[5]);
                f = __half22float2(*(const __half2*)&r0.w); a[6] = fmaf(n0, f.x, a[6]); a[7] = fmaf(n0, f.y, a[7]);
                f = __half22float2(*(const __half2*)&r1.x); b[0] = fmaf(n1, f.x, b[0]); b[1] = fmaf(n1, f.y, b[1]);
                f = __half22float2(*(const __half2*)&r1.y); b[2] = fmaf(n1, f.x, b[2]); b[3] = fmaf(n1, f.y, b[3]);
                f = __half22float2(*(const __half2*)&r1.z); b[4] = fmaf(n1, f.x, b[4]); b[5] = fmaf(n1, f.y, b[5]);
                f = __half22float2(*(const __half2*)&r1.w); b[6] = fmaf(n1, f.x, b[6]); b[7] = fmaf(n1, f.y, b[7]);
                f = __half22float2(*(const __half2*)&r2.x); cA[0] = fmaf(n2, f.x, cA[0]); cA[1] = fmaf(n2, f.y, cA[1]);
                f = __half22float2(*(const __half2*)&r2.y); cA[2] = fmaf(n2, f.x, cA[2]); cA[3] = fmaf(n2, f.y, cA[3]);
                f = __half22float2(*(const __half2*)&r2.z); cA[4] = fmaf(n2, f.x, cA[4]); cA[5] = fmaf(n2, f.y, cA[5]);
                f = __half22float2(*(const __half2*)&r2.w); cA[6] = fmaf(n2, f.x, cA[6]); cA[7] = fmaf(n2, f.y, cA[7]);
                f = __half22float2(*(const __half2*)&r3.x); dA[0] = fmaf(n3, f.x, dA[0]); dA[1] = fmaf(n3, f.y, dA[1]);
                f = __half22float2(*(const __half2*)&r3.y); dA[2] = fmaf(n3, f.x, dA[2]); dA[3] = fmaf(n3, f.y, dA[3]);
                f = __half22float2(*(const __half2*)&r3.z); dA[4] = fmaf(n3, f.x, dA[4]); dA[5] = fmaf(n3, f.y, dA[5]);
                f = __half22float2(*(const __half2*)&r3.w); dA[6] = fmaf(n3, f.x, dA[6]); dA[7] = fmaf(n3, f.y, dA[7]);
            }
        }
#pragma unroll
        for (int i = 0; i < 8; ++i) a[i] += b[i] + cA[i] + dA[i];
#pragma unroll
        for (int mlt = 16; mlt <= 32; mlt <<= 1) {
#pragma unroll
            for (int i = 0; i < 8; ++i) a[i] += __shfl_xor(a[i], mlt);
        }
        if (grp == 0) {
            int ch = c4 * 8;
            float dv = dinv[v];
            float ns = dv * dv;
            uint4 r = hw4[(size_t)v * 16 + c4];
            float2 f;
            f = __half22float2(*(const __half2*)&r.x); a[0] = fmaf(ns, f.x, a[0]); a[1] = fmaf(ns, f.y, a[1]);
            f = __half22float2(*(const __half2*)&r.y); a[2] = fmaf(ns, f.x, a[2]); a[3] = fmaf(ns, f.y, a[3]);
            f = __half22float2(*(const __half2*)&r.z); a[4] = fmaf(ns, f.x, a[4]); a[5] = fmaf(ns, f.y, a[5]);
            f = __half22float2(*(const __half2*)&r.w); a[6] = fmaf(ns, f.x, a[6]); a[7] = fmaf(ns, f.y, a[7]);
#pragma unroll
            for (int i = 0; i < 8; ++i) a[i] += bias[ch + i];
#pragma unroll
            for (int i = 0; i < 8; ++i) {
                int c = ch + i;
                float sc = gamma[c] * rsqrtf(rvar[c] + BN_EPS);
                a[i] = fmaxf((a[i] - rmean[c]) * sc + beta[c], 0.f);
            }
            int rloc = wave * 8 + nn;
            ushort4 oh0, oh1, ol0, ol1;
            oh0.x = f2bf(a[0]); ol0.x = f2bf(a[0] - bf2f(oh0.x));
            oh0.y = f2bf(a[1]); ol0.y = f2bf(a[1] - bf2f(oh0.y));
            oh0.z = f2bf(a[2]); ol0.z = f2bf(a[2] - bf2f(oh0.z));
            oh0.w = f2bf(a[3]); ol0.w = f2bf(a[3] - bf2f(oh0.w));
            oh1.x = f2bf(a[4]); ol1.x = f2bf(a[4] - bf2f(oh1.x));
            oh1.y = f2bf(a[5]); ol1.y = f2bf(a[5] - bf2f(oh1.y));
            oh1.z = f2bf(a[6]); ol1.z = f2bf(a[6] - bf2f(oh1.z));
            oh1.w = f2bf(a[7]); ol1.w = f2bf(a[7] - bf2f(oh1.w));
            *(ushort4*)&lh[rloc][ch]     = oh0;
            *(ushort4*)&lh[rloc][ch + 4] = oh1;
            *(ushort4*)&ll[rloc][ch]     = ol0;
            *(ushort4*)&ll[rloc][ch + 4] = ol1;
        }
    }
    __syncthreads();
    int quad = lane >> 4, m = lane & 15;
    f32x4 acc[2][2] = {};
    int kq = quad * 8;
#pragma unroll
    for (int t = 0; t < 4; ++t) {
        int k0 = t * 32 + kq;
        short8 a0h = *(const short8*)&lh[m][k0];
        short8 a0l = *(const short8*)&ll[m][k0];
        short8 a1h = *(const short8*)&lh[16 + m][k0];
        short8 a1l = *(const short8*)&ll[16 + m][k0];
#pragma unroll
        for (int c = 0; c < 2; ++c) {
            int ct = wave * 2 + c;
            short8 bh = *(const short8*)(WThi + (size_t)(ct * 16 + m) * HH + k0);
            short8 bl = *(const short8*)(WTlo + (size_t)(ct * 16 + m) * HH + k0);
            acc[0][c] = __builtin_amdgcn_mfma_f32_16x16x32_bf16(a0h, bh, acc[0][c], 0, 0, 0);
            acc[0][c] = __builtin_amdgcn_mfma_f32_16x16x32_bf16(a0l, bh, acc[0][c], 0, 0, 0);
            acc[0][c] = __builtin_amdgcn_mfma_f32_16x16x32_bf16(a0h, bl, acc[0][c], 0, 0, 0);
            acc[1][c] = __builtin_amdgcn_mfma_f32_16x16x32_bf16(a1h, bh, acc[1][c], 0, 0, 0);
            acc[1][c] = __builtin_amdgcn_mfma_f32_16x16x32_bf16(a1l, bh, acc[1][c], 0, 0, 0);
            acc[1][c] = __builtin_amdgcn_mfma_f32_16x16x32_bf16(a1h, bl, acc[1][c], 0, 0, 0);
        }
    }
#pragma unroll
    for (int c = 0; c < 2; ++c) {
        int colx = (wave * 2 + c) * 16 + m;
#pragma unroll
        for (int rt = 0; rt < 2; ++rt) {
            int r0 = nodebase + rt * 16 + quad * 4;
#pragma unroll
            for (int reg = 0; reg < 4; ++reg)
                hw_out[(size_t)(r0 + reg) * HH + colx] = __float2half(acc[rt][c][reg]);
        }
    }
}

// ---------------- Fused: last aggregate (bias only) + per-graph pooling partials ----------------
__global__ __launch_bounds__(256) void agg_pool_kernel(const __half* __restrict__ hw_in,
    const int* __restrict__ row_ptr, const int2* __restrict__ col,
    const float* __restrict__ dinv, const float* __restrict__ bias,
    const int* __restrict__ batch, float* __restrict__ pooled) {
    __shared__ __align__(16) float lf[32][132];
    __shared__ int bg[32];
    int wave = threadIdx.x >> 6;
    int lane = threadIdx.x & 63;
    int grp = lane >> 4;
    int c4 = lane & 15;
    int nodebase = blockIdx.x * 32;
    const uint4* hw4 = (const uint4*)hw_in;

    for (int nn = 0; nn < 8; ++nn) {
        int v = nodebase + wave * 8 + nn;
        int start = row_ptr[v], end = row_ptr[v + 1];
        float a[8] = {}, b[8] = {}, cA[8] = {}, dA[8] = {};
        for (int j0 = start; j0 < end; j0 += 64) {
            int jj = j0 + lane;
            int sp = 0; float np = 0.f;
            if (jj < end) {
                unsigned long long w = __builtin_nontemporal_load((const unsigned long long*)&col[jj]);
                sp = (int)(unsigned)(w & 0xffffffffu);
                np = __int_as_float((int)(unsigned)(w >> 32));
            }
            int rem = min(64, end - j0);
            int nb = (rem + 15) >> 4;
            for (int it = 0; it < nb; ++it) {
                int e0 = it * 16 + grp;
                int s0 = __shfl(sp, e0),      s1 = __shfl(sp, e0 + 4);
                int s2 = __shfl(sp, e0 + 8),  s3 = __shfl(sp, e0 + 12);
                float n0 = __shfl(np, e0),     n1 = __shfl(np, e0 + 4);
                float n2 = __shfl(np, e0 + 8), n3 = __shfl(np, e0 + 12);
                uint4 r0 = hw4[(size_t)s0 * 16 + c4];
                uint4 r1 = hw4[(size_t)s1 * 16 + c4];
                uint4 r2 = hw4[(size_t)s2 * 16 + c4];
                uint4 r3 = hw4[(size_t)s3 * 16 + c4];
                float2 f;
                f = __half22float2(*(const __half2*)&r0.x); a[0] = fmaf(n0, f.x, a[0]); a[1] = fmaf(n0, f.y, a[1]);
                f = __half22float2(*(const __half2*)&r0.y); a[2] = fmaf(n0, f.x, a[2]); a[3] = fmaf(n0, f.y, a[3]);
                f = __half22float2(*(const __half2*)&r0.z); a[4] = fmaf(n0, f.x, a[4]); a[5] = fmaf(n0, f.y, a[5]);
                f = __half22float2(*(const __half2*)&r0.w); a[6] = fmaf(n0, f.x, a[6]); a[7] = fmaf(n0, f.y, a[7]);
                f = __half22float2(*(const __half2*)&r1.x); b[0] = fmaf(n1, f.x, b[0]); b[1] = fmaf(n1, f.y, b[1]);
                f = __half22float2(*(const __half2*)&r1.y); b[2] = fmaf(n1, f.x, b[2]); b[3] = fmaf(n1, f.y, b[3]);
                f = __half22float2(*(const __half2*)&r1.z); b[4] = fmaf(n1, f.x, b[4]); b[5] = fmaf(n1, f.y, b[5]);
                f = __half22float2(*(const __half2*)&r1.w); b[6] = fmaf(n1, f.x, b[6]); b[7] = fmaf(n1, f.y, b[7]);
                f = __half22float2(*(const __half2*)&r2.x); cA[0] = fmaf(n2, f.x, cA[0]); cA[1] = fmaf(n2, f.y, cA[1]);
                f = __half22float2(*(const __half2*)&r2.y); cA[2] = fmaf(n2, f.x, cA[2]); cA[3] = fmaf(n2, f.y, cA[3]);
                f = __half22float2(*(const __half2*)&r2.z); cA[4] = fmaf(n2, f.x, cA[4]); cA[5] = fmaf(n2, f.y, cA[5]);
                f = __half22float2(*(const __half2*)&r2.w); cA[6] = fmaf(n2, f.x, cA[6]); cA[7] = fmaf(n2, f.y, cA[7]);
                f = __half22float2(*(const __half2*)&r3.x); dA[0] = fmaf(n3, f.x, dA[0]); dA[1] = fmaf(n3, f.y, dA[1]);
                f = __half22float2(*(const __half2*)&r3.y); dA[2] = fmaf(n3, f.x, dA[2]); dA[3] = fmaf(n3, f.y, dA[3]);
                f = __half22float2(*(const __half2*)&r3.z); dA[4] = fmaf(n3, f.x, dA[4]); dA[5] = fmaf(n3, f.y, dA[5]);
                f = __half22float2(*(const __half2*)&r3.w); dA[6] = fmaf(n3, f.x, dA[6]); dA[7] = fmaf(n3, f.y, dA[7]);
            }
        }
#pragma unroll
        for (int i = 0; i < 8; ++i) a[i] += b[i] + cA[i] + dA[i];
#pragma unroll
        for (int mlt = 16; mlt <= 32; mlt <<= 1) {
#pragma unroll
            for (int i = 0; i < 8; ++i) a[i] += __shfl_xor(a[i], mlt);
        }
        if (grp == 0) {
            int ch = c4 * 8;
            float dv = dinv[v];
            float ns = dv * dv;
            uint4 r = hw4[(size_t)v * 16 + c4];
            float2 f;
            f = __half22float2(*(const __half2*)&r.x); a[0] = fmaf(ns, f.x, a[0]); a[1] = fmaf(ns, f.y, a[1]);
            f = __half22float2(*(const __half2*)&r.y); a[2] = fmaf(ns, f.x, a[2]); a[3] = fmaf(ns, f.y, a[3]);
            f = __half22float2(*(const __half2*)&r.z); a[4] = fmaf(ns, f.x, a[4]); a[5] = fmaf(ns, f.y, a[5]);
            f = __half22float2(*(const __half2*)&r.w); a[6] = fmaf(ns, f.x, a[6]); a[7] = fmaf(ns, f.y, a[7]);
            int rloc = wave * 8 + nn;
#pragma unroll
            for (int i = 0; i < 8; ++i) lf[rloc][ch + i] = a[i] + bias[ch + i];
            if (c4 == 0) bg[rloc] = batch[v];
        }
    }
    __syncthreads();
    int c = threadIdx.x & 127;
    int rh = threadIdx.x >> 7;
    int r0 = rh * 16;
    int curg = bg[r0];
    float run = 0.f;
    for (int r = r0; r < r0 + 16; ++r) {
        int gg = bg[r];
        if (gg != curg) {
            atomicAdd(&pooled[(size_t)curg * HH + c], run);
            run = 0.f; curg = gg;
        }
        run += lf[r][c];
    }
    atomicAdd(&pooled[(size_t)curg * HH + c], run);
}

// ---------------- mean + classifier ----------------
__global__ __launch_bounds__(128) void clf_kernel(const float* __restrict__ pooled,
    const int* __restrict__ batch, const float* __restrict__ Wc,
    const float* __restrict__ bc, float* __restrict__ out) {
    __shared__ float pl[HH];
    int g = blockIdx.x;
    int tid = threadIdx.x;
    int lo = 0, hi = NN;
    while (lo < hi) { int mid = (lo + hi) >> 1; if (batch[mid] < g) lo = mid + 1; else hi = mid; }
    int start = lo;
    lo = 0; hi = NN;
    int g1 = g + 1;
    while (lo < hi) { int mid = (lo + hi) >> 1; if (batch[mid] < g1) lo = mid + 1; else hi = mid; }
    float cnt = (float)(lo - start);
    pl[tid] = pooled[(size_t)g * HH + tid] / fmaxf(cnt, 1.0f);
    __syncthreads();
    if (tid < OUTD) {
        float acc = bc[tid];
#pragma unroll 16
        for (int c = 0; c < HH; ++c) acc += pl[c] * Wc[c * OUTD + tid];
        out[g * OUTD + tid] = acc;
    }
}

extern "C" void kernel_launch(void* const* d_in, const int* in_sizes, int n_in,
                              void* d_out, int out_size, void* d_ws, size_t ws_size,
                              hipStream_t stream) {
    const int*   x      = (const int*)d_in[0];
    const int*   eidx   = (const int*)d_in[1];
    const int*   batch  = (const int*)d_in[2];
    const float* emb    = (const float*)d_in[3];
    const float* Ws     = (const float*)d_in[4];
    const float* bs     = (const float*)d_in[5];
    const float* gamma  = (const float*)d_in[6];
    const float* beta   = (const float*)d_in[7];
    const float* rmean  = (const float*)d_in[8];
    const float* rvar   = (const float*)d_in[9];
    const float* Wclf   = (const float*)d_in[10];
    const float* bclf   = (const float*)d_in[11];
    float* out = (float*)d_out;

    const int* e_src = eidx;
    const int* e_dst = eidx + EE;

    char* ws = (char*)d_ws;
    size_t off = 0;
    auto take = [&](size_t bytes) -> void* {
        void* p = ws + off;
        off = (off + bytes + 255) & ~(size_t)255;
        return p;
    };
    float* dinv     = (float*)take((size_t)NN * 4);
    int*   cnt      = (int*)  take((size_t)NN * 4);
    int*   row_ptr  = (int*)  take((size_t)(NN + 1) * 4);
    int*   bsum     = (int*)  take((size_t)NB_SCAN * 4);
    int*   bcur     = (int*)  take((size_t)256 * 4);
    int*   bucket_edges = (int*)take((size_t)NBUCK * BCAP * 4);
    int2*  col      = (int2*) take((size_t)EE * 8);
    __half* hwA     = (__half*)take((size_t)NN * HH * 2);
    __half* hwB     = (__half*)take((size_t)NN * HH * 2);
    float* pooled   = (float*)take((size_t)GG * HH * 4);
    unsigned short* WThi = (unsigned short*)take((size_t)LL * HH * HH * 2);
    unsigned short* WTlo = (unsigned short*)take((size_t)LL * HH * HH * 2);

    hipMemsetAsync(bcur, 0, 256 * 4, stream);
    hipMemsetAsync(pooled, 0, (size_t)GG * HH * 4, stream);

    split_kernel<<<(EE + CHUNK - 1) / CHUNK, 256, 0, stream>>>(e_src, e_dst, bcur, bucket_edges);
    bhist_kernel<<<NBUCK, 256, 0, stream>>>(bcur, bucket_edges, cnt);
    scanA_kernel<<<NB_SCAN, 256, 0, stream>>>(cnt, bsum, dinv);
    scanB_kernel<<<1, 128, 0, stream>>>(bsum);
    scanC_kernel<<<NB_SCAN, 256, 0, stream>>>(cnt, bsum, row_ptr);
    cscatter_kernel<<<NBUCK, 256, 0, stream>>>(bcur, bucket_edges, row_ptr, dinv, col);
    wconv_kernel<<<(LL * HH * HH + 255) / 256, 256, 0, stream>>>(Ws, WThi, WTlo);

    // encoder -> LDS -> @ W0 -> hw1
    enc_mm_kernel<<<NN / 32, 256, 0, stream>>>(x, emb, WThi, WTlo, hwA);
    // layer 0: agg(hw1)+bias0+BN0+ReLU -> LDS -> @ W1 -> hw2
    agg_mm_kernel<<<NN / 32, 256, 0, stream>>>(hwA, row_ptr, col, dinv,
        bs, gamma, beta, rmean, rvar,
        WThi + (size_t)1 * HH * HH, WTlo + (size_t)1 * HH * HH, hwB);
    // layer 1: agg(hw2)+bias1+BN1+ReLU -> LDS -> @ W2 -> hw3
    agg_mm_kernel<<<NN / 32, 256, 0, stream>>>(hwB, row_ptr, col, dinv,
        bs + HH, gamma + HH, beta + HH, rmean + HH, rvar + HH,
        WThi + (size_t)2 * HH * HH, WTlo + (size_t)2 * HH * HH, hwA);
    // layer 2: agg(hw3)+bias2 -> pooling partials
    agg_pool_kernel<<<NN / 32, 256, 0, stream>>>(hwA, row_ptr, col, dinv,
        bs + 2 * HH, batch, pooled);

    clf_kernel<<<GG, 128, 0, stream>>>(pooled, batch, Wclf, bclf, out);
}

// Round 11
// 493.780 us; speedup vs baseline: 1.0657x; 1.0657x over previous
//
#include <hip/hip_runtime.h>
#include <hip/hip_bf16.h>
#include <hip/hip_fp16.h>

#define NN 100000      // nodes
#define EE 1600000     // edges
#define GG 1024        // graphs
#define NF 9
#define VV 128
#define HH 128
#define LL 3
#define OUTD 10
#define BN_EPS 1e-5f
#define NB_SCAN 98     // ceil(NN/1024)
#define NBUCK 196      // ceil(NN/512) buckets of 512 nodes
#define BCAP 12288     // bucket capacity (avg fill 8192)
#define CHUNK 4096     // edges per split block

typedef __attribute__((ext_vector_type(8))) short short8;   // 8 bf16 = 4 VGPRs
typedef __attribute__((ext_vector_type(4))) float f32x4;

__device__ inline unsigned short f2bf(float x) {          // RNE f32 -> bf16 bits
    unsigned u = __float_as_uint(x);
    unsigned r = (u + 0x7fffu + ((u >> 16) & 1u)) >> 16;
    return (unsigned short)r;
}
__device__ inline float bf2f(unsigned short b) { return __uint_as_float(((unsigned)b) << 16); }

// 8x v_fma_mix_f32: a[i] += f32(half_i(r)) * nm   (bit-identical to cvt+fmaf)
__device__ inline void mix8(float a[8], const uint4& r, float nm) {
    asm("v_fma_mix_f32 %0, %8, %12, %0 op_sel:[0,0,0] op_sel_hi:[1,0,0]\n\t"
        "v_fma_mix_f32 %1, %8, %12, %1 op_sel:[1,0,0] op_sel_hi:[1,0,0]\n\t"
        "v_fma_mix_f32 %2, %9, %12, %2 op_sel:[0,0,0] op_sel_hi:[1,0,0]\n\t"
        "v_fma_mix_f32 %3, %9, %12, %3 op_sel:[1,0,0] op_sel_hi:[1,0,0]\n\t"
        "v_fma_mix_f32 %4, %10, %12, %4 op_sel:[0,0,0] op_sel_hi:[1,0,0]\n\t"
        "v_fma_mix_f32 %5, %10, %12, %5 op_sel:[1,0,0] op_sel_hi:[1,0,0]\n\t"
        "v_fma_mix_f32 %6, %11, %12, %6 op_sel:[0,0,0] op_sel_hi:[1,0,0]\n\t"
        "v_fma_mix_f32 %7, %11, %12, %7 op_sel:[1,0,0] op_sel_hi:[1,0,0]"
        : "+v"(a[0]), "+v"(a[1]), "+v"(a[2]), "+v"(a[3]),
          "+v"(a[4]), "+v"(a[5]), "+v"(a[6]), "+v"(a[7])
        : "v"(r.x), "v"(r.y), "v"(r.z), "v"(r.w), "v"(nm));
}

// ---------------- Two-level CSR build ----------------
__global__ __launch_bounds__(256) void split_kernel(const int* __restrict__ src,
                                                    const int* __restrict__ dst,
                                                    int* __restrict__ bcur,
                                                    int* __restrict__ bucket_edges) {
    __shared__ int lcnt[256], loff[256], lcur[256], gbase[256], sh[256];
    __shared__ int stage[CHUNK];
    __shared__ unsigned char stageb[CHUNK];
    int tid = threadIdx.x;
    int cs = blockIdx.x * CHUNK;
    int n = min(CHUNK, EE - cs);
    lcnt[tid] = 0;
    __syncthreads();
    for (int i = tid; i < n; i += 256)
        atomicAdd(&lcnt[dst[cs + i] >> 9], 1);
    __syncthreads();
    int val = lcnt[tid];
    sh[tid] = val; __syncthreads();
    for (int d = 1; d < 256; d <<= 1) {
        int t = (tid >= d) ? sh[tid - d] : 0;
        __syncthreads();
        sh[tid] += t;
        __syncthreads();
    }
    loff[tid] = sh[tid] - val;
    lcur[tid] = sh[tid] - val;
    __syncthreads();
    for (int i = tid; i < n; i += 256) {
        int d = dst[cs + i], s = src[cs + i];
        int b = d >> 9;
        int p = atomicAdd(&lcur[b], 1);
        stage[p] = (s << 9) | (d & 511);
        stageb[p] = (unsigned char)b;
    }
    if (val > 0) gbase[tid] = atomicAdd(&bcur[tid], val);
    __syncthreads();
    for (int i = tid; i < n; i += 256) {
        int b = stageb[i];
        bucket_edges[(size_t)b * BCAP + gbase[b] + (i - loff[b])] = stage[i];
    }
}

__global__ __launch_bounds__(256) void bhist_kernel(const int* __restrict__ bcur,
                                                    const int* __restrict__ bucket_edges,
                                                    int* __restrict__ cnt) {
    __shared__ int lc[512];
    int b = blockIdx.x, tid = threadIdx.x;
    lc[tid] = 0; lc[tid + 256] = 0;
    __syncthreads();
    int n = bcur[b];
    const int* be = bucket_edges + (size_t)b * BCAP;
    for (int i = tid; i < n; i += 256) atomicAdd(&lc[be[i] & 511], 1);
    __syncthreads();
    int node = b * 512 + tid;
    if (node < NN) cnt[node] = lc[tid];
    node += 256;
    if (node < NN) cnt[node] = lc[tid + 256];
}

__global__ void scanA_kernel(const int* __restrict__ cnt, int* __restrict__ bsum,
                             float* __restrict__ dinv) {
    __shared__ int sh[256];
    int tid = threadIdx.x;
    int base = blockIdx.x * 1024 + tid * 4;
    int s = 0;
#pragma unroll
    for (int i = 0; i < 4; ++i) {
        int idx = base + i;
        if (idx < NN) {
            int c = cnt[idx];
            s += c;
            dinv[idx] = rsqrtf(1.0f + (float)c);
        }
    }
    sh[tid] = s; __syncthreads();
    for (int d = 128; d > 0; d >>= 1) { if (tid < d) sh[tid] += sh[tid + d]; __syncthreads(); }
    if (tid == 0) bsum[blockIdx.x] = sh[0];
}

__global__ void scanB_kernel(int* __restrict__ bsum) {
    __shared__ int sh[128];
    int tid = threadIdx.x;
    int v = (tid < NB_SCAN) ? bsum[tid] : 0;
    sh[tid] = v; __syncthreads();
    for (int d = 1; d < 128; d <<= 1) {
        int t = (tid >= d) ? sh[tid - d] : 0;
        __syncthreads();
        sh[tid] += t;
        __syncthreads();
    }
    if (tid < NB_SCAN) bsum[tid] = sh[tid] - v;
}

__global__ void scanC_kernel(const int* __restrict__ cnt, const int* __restrict__ bsum,
                             int* __restrict__ row_ptr) {
    __shared__ int sh[256];
    int tid = threadIdx.x;
    int base = blockIdx.x * 1024 + tid * 4;
    int v[4];
#pragma unroll
    for (int i = 0; i < 4; ++i) { int idx = base + i; v[i] = (idx < NN) ? cnt[idx] : 0; }
    int tsum = v[0] + v[1] + v[2] + v[3];
    sh[tid] = tsum; __syncthreads();
    for (int d = 1; d < 256; d <<= 1) {
        int t = (tid >= d) ? sh[tid - d] : 0;
        __syncthreads();
        sh[tid] += t;
        __syncthreads();
    }
    int excl = sh[tid] - tsum + bsum[blockIdx.x];
#pragma unroll
    for (int i = 0; i < 4; ++i) {
        int idx = base + i;
        if (idx < NN) row_ptr[idx] = excl;
        excl += v[i];
    }
    if (blockIdx.x == 0 && tid == 0) row_ptr[NN] = EE;
}

__global__ __launch_bounds__(256) void cscatter_kernel(const int* __restrict__ bcur,
                                                       const int* __restrict__ bucket_edges,
                                                       const int* __restrict__ row_ptr,
                                                       const float* __restrict__ dinv,
                                                       int2* __restrict__ col) {
    __shared__ int lcur[512];
    int b = blockIdx.x, tid = threadIdx.x;
    int node0 = b * 512;
#pragma unroll
    for (int k = 0; k < 2; ++k) {
        int j = tid + k * 256;
        int node = node0 + j;
        if (node < NN) lcur[j] = row_ptr[node];
    }
    __syncthreads();
    int n = bcur[b];
    const int* be = bucket_edges + (size_t)b * BCAP;
    for (int i = tid; i < n; i += 256) {
        int w = be[i];
        int j = w & 511;
        int s = (int)((unsigned)w >> 9);
        int p = atomicAdd(&lcur[j], 1);
        float nm = dinv[s] * dinv[node0 + j];
        col[p] = make_int2(s, __float_as_int(nm));
    }
}

// ---------------- W^T hi/lo conversion ----------------
__global__ void wconv_kernel(const float* __restrict__ Ws,
                             unsigned short* __restrict__ WThi,
                             unsigned short* __restrict__ WTlo) {
    int id = blockIdx.x * 256 + threadIdx.x;
    if (id >= LL * HH * HH) return;
    int layer = id >> 14;
    int rem = id & (HH * HH - 1);
    int k = rem >> 7, n = rem & 127;
    float w = Ws[id];
    unsigned short hi = f2bf(w);
    float lo = w - bf2f(hi);
    WThi[(size_t)layer * HH * HH + n * HH + k] = hi;   // transposed: [n][k]
    WTlo[(size_t)layer * HH * HH + n * HH + k] = f2bf(lo);
}

// ---------------- Fused: atom encoder -> LDS -> MFMA @ W0 -> hw ----------------
__global__ __launch_bounds__(256) void enc_mm_kernel(const int* __restrict__ x,
        const float* __restrict__ emb,
        const unsigned short* __restrict__ WThi, const unsigned short* __restrict__ WTlo,
        __half* __restrict__ hw_out) {
    __shared__ __align__(16) unsigned short lh[32][136];
    __shared__ __align__(16) unsigned short ll[32][136];
    int tid = threadIdx.x;
    int nloc = tid >> 3;           // 0..31
    int seg = tid & 7;             // 16-ch segment
    int nodebase = blockIdx.x * 32;
    int n = nodebase + nloc;
    float s[16];
#pragma unroll
    for (int i = 0; i < 16; ++i) s[i] = 0.f;
#pragma unroll
    for (int f = 0; f < NF; ++f) {
        int idx = x[n * NF + f];
        const float4* ep = (const float4*)(emb + ((size_t)(f * VV + idx)) * HH + seg * 16);
#pragma unroll
        for (int q = 0; q < 4; ++q) {
            float4 e = ep[q];
            s[q * 4 + 0] += e.x; s[q * 4 + 1] += e.y;
            s[q * 4 + 2] += e.z; s[q * 4 + 3] += e.w;
        }
    }
#pragma unroll
    for (int q = 0; q < 4; ++q) {
        ushort4 oh, ol;
        oh.x = f2bf(s[q * 4 + 0]); ol.x = f2bf(s[q * 4 + 0] - bf2f(oh.x));
        oh.y = f2bf(s[q * 4 + 1]); ol.y = f2bf(s[q * 4 + 1] - bf2f(oh.y));
        oh.z = f2bf(s[q * 4 + 2]); ol.z = f2bf(s[q * 4 + 2] - bf2f(oh.z));
        oh.w = f2bf(s[q * 4 + 3]); ol.w = f2bf(s[q * 4 + 3] - bf2f(oh.w));
        *(ushort4*)&lh[nloc][seg * 16 + q * 4] = oh;
        *(ushort4*)&ll[nloc][seg * 16 + q * 4] = ol;
    }
    __syncthreads();
    int wave = tid >> 6, lane = tid & 63;
    int quad = lane >> 4, m = lane & 15;
    f32x4 acc[2][2] = {};
    int kq = quad * 8;
#pragma unroll
    for (int t = 0; t < 4; ++t) {
        int k0 = t * 32 + kq;
        short8 a0h = *(const short8*)&lh[m][k0];
        short8 a0l = *(const short8*)&ll[m][k0];
        short8 a1h = *(const short8*)&lh[16 + m][k0];
        short8 a1l = *(const short8*)&ll[16 + m][k0];
#pragma unroll
        for (int c = 0; c < 2; ++c) {
            int ct = wave * 2 + c;
            short8 bh = *(const short8*)(WThi + (size_t)(ct * 16 + m) * HH + k0);
            short8 bl = *(const short8*)(WTlo + (size_t)(ct * 16 + m) * HH + k0);
            acc[0][c] = __builtin_amdgcn_mfma_f32_16x16x32_bf16(a0h, bh, acc[0][c], 0, 0, 0);
            acc[0][c] = __builtin_amdgcn_mfma_f32_16x16x32_bf16(a0l, bh, acc[0][c], 0, 0, 0);
            acc[0][c] = __builtin_amdgcn_mfma_f32_16x16x32_bf16(a0h, bl, acc[0][c], 0, 0, 0);
            acc[1][c] = __builtin_amdgcn_mfma_f32_16x16x32_bf16(a1h, bh, acc[1][c], 0, 0, 0);
            acc[1][c] = __builtin_amdgcn_mfma_f32_16x16x32_bf16(a1l, bh, acc[1][c], 0, 0, 0);
            acc[1][c] = __builtin_amdgcn_mfma_f32_16x16x32_bf16(a1h, bl, acc[1][c], 0, 0, 0);
        }
    }
#pragma unroll
    for (int c = 0; c < 2; ++c) {
        int colx = (wave * 2 + c) * 16 + m;
#pragma unroll
        for (int rt = 0; rt < 2; ++rt) {
            int r0 = nodebase + rt * 16 + quad * 4;
#pragma unroll
            for (int reg = 0; reg < 4; ++reg)
                hw_out[(size_t)(r0 + reg) * HH + colx] = __float2half(acc[rt][c][reg]);
        }
    }
}

// ---------------- Fused: CSR aggregate + bias + BN + ReLU -> LDS -> MFMA @ Wnext ----------------
// Gather: unroll-2 (round-9 proven), inner FMAs via v_fma_mix_f32.
__global__ __launch_bounds__(256) void agg_mm_kernel(const __half* __restrict__ hw_in,
    const int* __restrict__ row_ptr, const int2* __restrict__ col,
    const float* __restrict__ dinv,
    const float* __restrict__ bias, const float* __restrict__ gamma,
    const float* __restrict__ beta, const float* __restrict__ rmean,
    const float* __restrict__ rvar,
    const unsigned short* __restrict__ WThi, const unsigned short* __restrict__ WTlo,
    __half* __restrict__ hw_out) {
    __shared__ __align__(16) unsigned short lh[32][136];
    __shared__ __align__(16) unsigned short ll[32][136];
    int wave = threadIdx.x >> 6;
    int lane = threadIdx.x & 63;
    int grp = lane >> 4;             // 0..3
    int c4 = lane & 15;
    int nodebase = blockIdx.x * 32;
    const uint4* hw4 = (const uint4*)hw_in;

    for (int nn = 0; nn < 8; ++nn) {
        int v = nodebase + wave * 8 + nn;
        int start = row_ptr[v], end = row_ptr[v + 1];
        float a[8] = {}, b[8] = {};
        for (int j0 = start; j0 < end; j0 += 64) {
            int jj = j0 + lane;
            int sp = 0; float np = 0.f;
            if (jj < end) {
                unsigned long long w = __builtin_nontemporal_load((const unsigned long long*)&col[jj]);
                sp = (int)(unsigned)(w & 0xffffffffu);
                np = __int_as_float((int)(unsigned)(w >> 32));
            }
            int rem = min(64, end - j0);
            int iters = (rem + 3) >> 2;
            int it = 0;
            for (; it + 2 <= iters; it += 2) {
                int i0 = it * 4 + grp, i1 = i0 + 4;
                int s0 = __shfl(sp, i0), s1 = __shfl(sp, i1);
                float n0 = __shfl(np, i0), n1 = __shfl(np, i1);
                uint4 r0 = hw4[(size_t)s0 * 16 + c4];
                uint4 r1 = hw4[(size_t)s1 * 16 + c4];
                mix8(a, r0, n0);
                mix8(b, r1, n1);
            }
            if (it < iters) {
                int i0 = it * 4 + grp;
                int s0 = __shfl(sp, i0);
                float n0 = __shfl(np, i0);
                uint4 r0 = hw4[(size_t)s0 * 16 + c4];
                mix8(a, r0, n0);
            }
        }
#pragma unroll
        for (int i = 0; i < 8; ++i) a[i] += b[i];
#pragma unroll
        for (int mlt = 16; mlt <= 32; mlt <<= 1) {
#pragma unroll
            for (int i = 0; i < 8; ++i) a[i] += __shfl_xor(a[i], mlt);
        }
        if (grp == 0) {
            int ch = c4 * 8;
            float dv = dinv[v];
            float ns = dv * dv;
            uint4 r = hw4[(size_t)v * 16 + c4];
            mix8(a, r, ns);
#pragma unroll
            for (int i = 0; i < 8; ++i) a[i] += bias[ch + i];
#pragma unroll
            for (int i = 0; i < 8; ++i) {
                int c = ch + i;
                float sc = gamma[c] * rsqrtf(rvar[c] + BN_EPS);
                a[i] = fmaxf((a[i] - rmean[c]) * sc + beta[c], 0.f);
            }
            int rloc = wave * 8 + nn;
            ushort4 oh0, oh1, ol0, ol1;
            oh0.x = f2bf(a[0]); ol0.x = f2bf(a[0] - bf2f(oh0.x));
            oh0.y = f2bf(a[1]); ol0.y = f2bf(a[1] - bf2f(oh0.y));
            oh0.z = f2bf(a[2]); ol0.z = f2bf(a[2] - bf2f(oh0.z));
            oh0.w = f2bf(a[3]); ol0.w = f2bf(a[3] - bf2f(oh0.w));
            oh1.x = f2bf(a[4]); ol1.x = f2bf(a[4] - bf2f(oh1.x));
            oh1.y = f2bf(a[5]); ol1.y = f2bf(a[5] - bf2f(oh1.y));
            oh1.z = f2bf(a[6]); ol1.z = f2bf(a[6] - bf2f(oh1.z));
            oh1.w = f2bf(a[7]); ol1.w = f2bf(a[7] - bf2f(oh1.w));
            *(ushort4*)&lh[rloc][ch]     = oh0;
            *(ushort4*)&lh[rloc][ch + 4] = oh1;
            *(ushort4*)&ll[rloc][ch]     = ol0;
            *(ushort4*)&ll[rloc][ch + 4] = ol1;
        }
    }
    __syncthreads();
    int quad = lane >> 4, m = lane & 15;
    f32x4 acc[2][2] = {};
    int kq = quad * 8;
#pragma unroll
    for (int t = 0; t < 4; ++t) {
        int k0 = t * 32 + kq;
        short8 a0h = *(const short8*)&lh[m][k0];
        short8 a0l = *(const short8*)&ll[m][k0];
        short8 a1h = *(const short8*)&lh[16 + m][k0];
        short8 a1l = *(const short8*)&ll[16 + m][k0];
#pragma unroll
        for (int c = 0; c < 2; ++c) {
            int ct = wave * 2 + c;
            short8 bh = *(const short8*)(WThi + (size_t)(ct * 16 + m) * HH + k0);
            short8 bl = *(const short8*)(WTlo + (size_t)(ct * 16 + m) * HH + k0);
            acc[0][c] = __builtin_amdgcn_mfma_f32_16x16x32_bf16(a0h, bh, acc[0][c], 0, 0, 0);
            acc[0][c] = __builtin_amdgcn_mfma_f32_16x16x32_bf16(a0l, bh, acc[0][c], 0, 0, 0);
            acc[0][c] = __builtin_amdgcn_mfma_f32_16x16x32_bf16(a0h, bl, acc[0][c], 0, 0, 0);
            acc[1][c] = __builtin_amdgcn_mfma_f32_16x16x32_bf16(a1h, bh, acc[1][c], 0, 0, 0);
            acc[1][c] = __builtin_amdgcn_mfma_f32_16x16x32_bf16(a1l, bh, acc[1][c], 0, 0, 0);
            acc[1][c] = __builtin_amdgcn_mfma_f32_16x16x32_bf16(a1h, bl, acc[1][c], 0, 0, 0);
        }
    }
#pragma unroll
    for (int c = 0; c < 2; ++c) {
        int colx = (wave * 2 + c) * 16 + m;
#pragma unroll
        for (int rt = 0; rt < 2; ++rt) {
            int r0 = nodebase + rt * 16 + quad * 4;
#pragma unroll
            for (int reg = 0; reg < 4; ++reg)
                hw_out[(size_t)(r0 + reg) * HH + colx] = __float2half(acc[rt][c][reg]);
        }
    }
}

// ---------------- Fused: last aggregate (bias only) + per-graph pooling partials ----------------
__global__ __launch_bounds__(256) void agg_pool_kernel(const __half* __restrict__ hw_in,
    const int* __restrict__ row_ptr, const int2* __restrict__ col,
    const float* __restrict__ dinv, const float* __restrict__ bias,
    const int* __restrict__ batch, float* __restrict__ pooled) {
    __shared__ __align__(16) float lf[32][132];
    __shared__ int bg[32];
    int wave = threadIdx.x >> 6;
    int lane = threadIdx.x & 63;
    int grp = lane >> 4;
    int c4 = lane & 15;
    int nodebase = blockIdx.x * 32;
    const uint4* hw4 = (const uint4*)hw_in;

    for (int nn = 0; nn < 8; ++nn) {
        int v = nodebase + wave * 8 + nn;
        int start = row_ptr[v], end = row_ptr[v + 1];
        float a[8] = {}, b[8] = {};
        for (int j0 = start; j0 < end; j0 += 64) {
            int jj = j0 + lane;
            int sp = 0; float np = 0.f;
            if (jj < end) {
                unsigned long long w = __builtin_nontemporal_load((const unsigned long long*)&col[jj]);
                sp = (int)(unsigned)(w & 0xffffffffu);
                np = __int_as_float((int)(unsigned)(w >> 32));
            }
            int rem = min(64, end - j0);
            int iters = (rem + 3) >> 2;
            int it = 0;
            for (; it + 2 <= iters; it += 2) {
                int i0 = it * 4 + grp, i1 = i0 + 4;
                int s0 = __shfl(sp, i0), s1 = __shfl(sp, i1);
                float n0 = __shfl(np, i0), n1 = __shfl(np, i1);
                uint4 r0 = hw4[(size_t)s0 * 16 + c4];
                uint4 r1 = hw4[(size_t)s1 * 16 + c4];
                mix8(a, r0, n0);
                mix8(b, r1, n1);
            }
            if (it < iters) {
                int i0 = it * 4 + grp;
                int s0 = __shfl(sp, i0);
                float n0 = __shfl(np, i0);
                uint4 r0 = hw4[(size_t)s0 * 16 + c4];
                mix8(a, r0, n0);
            }
        }
#pragma unroll
        for (int i = 0; i < 8; ++i) a[i] += b[i];
#pragma unroll
        for (int mlt = 16; mlt <= 32; mlt <<= 1) {
#pragma unroll
            for (int i = 0; i < 8; ++i) a[i] += __shfl_xor(a[i], mlt);
        }
        if (grp == 0) {
            int ch = c4 * 8;
            float dv = dinv[v];
            float ns = dv * dv;
            uint4 r = hw4[(size_t)v * 16 + c4];
            mix8(a, r, ns);
            int rloc = wave * 8 + nn;
#pragma unroll
            for (int i = 0; i < 8; ++i) lf[rloc][ch + i] = a[i] + bias[ch + i];
            if (c4 == 0) bg[rloc] = batch[v];
        }
    }
    __syncthreads();
    int c = threadIdx.x & 127;
    int rh = threadIdx.x >> 7;
    int r0 = rh * 16;
    int curg = bg[r0];
    float run = 0.f;
    for (int r = r0; r < r0 + 16; ++r) {
        int gg = bg[r];
        if (gg != curg) {
            atomicAdd(&pooled[(size_t)curg * HH + c], run);
            run = 0.f; curg = gg;
        }
        run += lf[r][c];
    }
    atomicAdd(&pooled[(size_t)curg * HH + c], run);
}

// ---------------- mean + classifier ----------------
__global__ __launch_bounds__(128) void clf_kernel(const float* __restrict__ pooled,
    const int* __restrict__ batch, const float* __restrict__ Wc,
    const float* __restrict__ bc, float* __restrict__ out) {
    __shared__ float pl[HH];
    int g = blockIdx.x;
    int tid = threadIdx.x;
    int lo = 0, hi = NN;
    while (lo < hi) { int mid = (lo + hi) >> 1; if (batch[mid] < g) lo = mid + 1; else hi = mid; }
    int start = lo;
    lo = 0; hi = NN;
    int g1 = g + 1;
    while (lo < hi) { int mid = (lo + hi) >> 1; if (batch[mid] < g1) lo = mid + 1; else hi = mid; }
    float cnt = (float)(lo - start);
    pl[tid] = pooled[(size_t)g * HH + tid] / fmaxf(cnt, 1.0f);
    __syncthreads();
    if (tid < OUTD) {
        float acc = bc[tid];
#pragma unroll 16
        for (int c = 0; c < HH; ++c) acc += pl[c] * Wc[c * OUTD + tid];
        out[g * OUTD + tid] = acc;
    }
}

extern "C" void kernel_launch(void* const* d_in, const int* in_sizes, int n_in,
                              void* d_out, int out_size, void* d_ws, size_t ws_size,
                              hipStream_t stream) {
    const int*   x      = (const int*)d_in[0];
    const int*   eidx   = (const int*)d_in[1];
    const int*   batch  = (const int*)d_in[2];
    const float* emb    = (const float*)d_in[3];
    const float* Ws     = (const float*)d_in[4];
    const float* bs     = (const float*)d_in[5];
    const float* gamma  = (const float*)d_in[6];
    const float* beta   = (const float*)d_in[7];
    const float* rmean  = (const float*)d_in[8];
    const float* rvar   = (const float*)d_in[9];
    const float* Wclf   = (const float*)d_in[10];
    const float* bclf   = (const float*)d_in[11];
    float* out = (float*)d_out;

    const int* e_src = eidx;
    const int* e_dst = eidx + EE;

    char* ws = (char*)d_ws;
    size_t off = 0;
    auto take = [&](size_t bytes) -> void* {
        void* p = ws + off;
        off = (off + bytes + 255) & ~(size_t)255;
        return p;
    };
    float* dinv     = (float*)take((size_t)NN * 4);
    int*   cnt      = (int*)  take((size_t)NN * 4);
    int*   row_ptr  = (int*)  take((size_t)(NN + 1) * 4);
    int*   bsum     = (int*)  take((size_t)NB_SCAN * 4);
    int*   bcur     = (int*)  take((size_t)256 * 4);
    int*   bucket_edges = (int*)take((size_t)NBUCK * BCAP * 4);
    int2*  col      = (int2*) take((size_t)EE * 8);
    __half* hwA     = (__half*)take((size_t)NN * HH * 2);
    __half* hwB     = (__half*)take((size_t)NN * HH * 2);
    float* pooled   = (float*)take((size_t)GG * HH * 4);
    unsigned short* WThi = (unsigned short*)take((size_t)LL * HH * HH * 2);
    unsigned short* WTlo = (unsigned short*)take((size_t)LL * HH * HH * 2);

    hipMemsetAsync(bcur, 0, 256 * 4, stream);
    hipMemsetAsync(pooled, 0, (size_t)GG * HH * 4, stream);

    split_kernel<<<(EE + CHUNK - 1) / CHUNK, 256, 0, stream>>>(e_src, e_dst, bcur, bucket_edges);
    bhist_kernel<<<NBUCK, 256, 0, stream>>>(bcur, bucket_edges, cnt);
    scanA_kernel<<<NB_SCAN, 256, 0, stream>>>(cnt, bsum, dinv);
    scanB_kernel<<<1, 128, 0, stream>>>(bsum);
    scanC_kernel<<<NB_SCAN, 256, 0, stream>>>(cnt, bsum, row_ptr);
    cscatter_kernel<<<NBUCK, 256, 0, stream>>>(bcur, bucket_edges, row_ptr, dinv, col);
    wconv_kernel<<<(LL * HH * HH + 255) / 256, 256, 0, stream>>>(Ws, WThi, WTlo);

    // encoder -> LDS -> @ W0 -> hw1
    enc_mm_kernel<<<NN / 32, 256, 0, stream>>>(x, emb, WThi, WTlo, hwA);
    // layer 0: agg(hw1)+bias0+BN0+ReLU -> LDS -> @ W1 -> hw2
    agg_mm_kernel<<<NN / 32, 256, 0, stream>>>(hwA, row_ptr, col, dinv,
        bs, gamma, beta, rmean, rvar,
        WThi + (size_t)1 * HH * HH, WTlo + (size_t)1 * HH * HH, hwB);
    // layer 1: agg(hw2)+bias1+BN1+ReLU -> LDS -> @ W2 -> hw3
    agg_mm_kernel<<<NN / 32, 256, 0, stream>>>(hwB, row_ptr, col, dinv,
        bs + HH, gamma + HH, beta + HH, rmean + HH, rvar + HH,
        WThi + (size_t)2 * HH * HH, WTlo + (size_t)2 * HH * HH, hwA);
    // layer 2: agg(hw3)+bias2 -> pooling partials
    agg_pool_kernel<<<NN / 32, 256, 0, stream>>>(hwA, row_ptr, col, dinv,
        bs + 2 * HH, batch, pooled);

    clf_kernel<<<GG, 128, 0, stream>>>(pooled, batch, Wclf, bclf, out);
}

// Round 12
// 484.274 us; speedup vs baseline: 1.0866x; 1.0196x over previous
//
#include <hip/hip_runtime.h>
#include <hip/hip_bf16.h>
#include <hip/hip_fp16.h>

#define NN 100000      // nodes
#define EE 1600000     // edges
#define GG 1024        // graphs
#define NF 9
#define VV 128
#define HH 128
#define LL 3
#define OUTD 10
#define BN_EPS 1e-5f
#define NB_SCAN 98     // ceil(NN/1024)
#define NBUCK 196      // ceil(NN/512) buckets of 512 nodes
#define BCAP 12288     // bucket capacity (avg fill 8192)
#define CHUNK 4096     // edges per split block

typedef __attribute__((ext_vector_type(8))) short short8;   // 8 bf16 = 4 VGPRs
typedef __attribute__((ext_vector_type(4))) float f32x4;

__device__ inline unsigned short f2bf(float x) {          // RNE f32 -> bf16 bits
    unsigned u = __float_as_uint(x);
    unsigned r = (u + 0x7fffu + ((u >> 16) & 1u)) >> 16;
    return (unsigned short)r;
}
__device__ inline float bf2f(unsigned short b) { return __uint_as_float(((unsigned)b) << 16); }

// 8x v_fma_mix_f32: a[i] += f32(half_i(r)) * nm   (bit-identical to cvt+fmaf)
__device__ inline void mix8(float a[8], const uint4& r, float nm) {
    asm("v_fma_mix_f32 %0, %8, %12, %0 op_sel:[0,0,0] op_sel_hi:[1,0,0]\n\t"
        "v_fma_mix_f32 %1, %8, %12, %1 op_sel:[1,0,0] op_sel_hi:[1,0,0]\n\t"
        "v_fma_mix_f32 %2, %9, %12, %2 op_sel:[0,0,0] op_sel_hi:[1,0,0]\n\t"
        "v_fma_mix_f32 %3, %9, %12, %3 op_sel:[1,0,0] op_sel_hi:[1,0,0]\n\t"
        "v_fma_mix_f32 %4, %10, %12, %4 op_sel:[0,0,0] op_sel_hi:[1,0,0]\n\t"
        "v_fma_mix_f32 %5, %10, %12, %5 op_sel:[1,0,0] op_sel_hi:[1,0,0]\n\t"
        "v_fma_mix_f32 %6, %11, %12, %6 op_sel:[0,0,0] op_sel_hi:[1,0,0]\n\t"
        "v_fma_mix_f32 %7, %11, %12, %7 op_sel:[1,0,0] op_sel_hi:[1,0,0]"
        : "+v"(a[0]), "+v"(a[1]), "+v"(a[2]), "+v"(a[3]),
          "+v"(a[4]), "+v"(a[5]), "+v"(a[6]), "+v"(a[7])
        : "v"(r.x), "v"(r.y), "v"(r.z), "v"(r.w), "v"(nm));
}

// ---------------- Two-level CSR build ----------------
__global__ __launch_bounds__(256) void split_kernel(const int* __restrict__ src,
                                                    const int* __restrict__ dst,
                                                    int* __restrict__ bcur,
                                                    int* __restrict__ bucket_edges) {
    __shared__ int lcnt[256], loff[256], lcur[256], gbase[256], sh[256];
    __shared__ int stage[CHUNK];
    __shared__ unsigned char stageb[CHUNK];
    int tid = threadIdx.x;
    int cs = blockIdx.x * CHUNK;
    int n = min(CHUNK, EE - cs);
    lcnt[tid] = 0;
    __syncthreads();
    for (int i = tid; i < n; i += 256)
        atomicAdd(&lcnt[dst[cs + i] >> 9], 1);
    __syncthreads();
    int val = lcnt[tid];
    sh[tid] = val; __syncthreads();
    for (int d = 1; d < 256; d <<= 1) {
        int t = (tid >= d) ? sh[tid - d] : 0;
        __syncthreads();
        sh[tid] += t;
        __syncthreads();
    }
    loff[tid] = sh[tid] - val;
    lcur[tid] = sh[tid] - val;
    __syncthreads();
    for (int i = tid; i < n; i += 256) {
        int d = dst[cs + i], s = src[cs + i];
        int b = d >> 9;
        int p = atomicAdd(&lcur[b], 1);
        stage[p] = (s << 9) | (d & 511);
        stageb[p] = (unsigned char)b;
    }
    if (val > 0) gbase[tid] = atomicAdd(&bcur[tid], val);
    __syncthreads();
    for (int i = tid; i < n; i += 256) {
        int b = stageb[i];
        bucket_edges[(size_t)b * BCAP + gbase[b] + (i - loff[b])] = stage[i];
    }
}

__global__ __launch_bounds__(256) void bhist_kernel(const int* __restrict__ bcur,
                                                    const int* __restrict__ bucket_edges,
                                                    int* __restrict__ cnt) {
    __shared__ int lc[512];
    int b = blockIdx.x, tid = threadIdx.x;
    lc[tid] = 0; lc[tid + 256] = 0;
    __syncthreads();
    int n = bcur[b];
    const int* be = bucket_edges + (size_t)b * BCAP;
    for (int i = tid; i < n; i += 256) atomicAdd(&lc[be[i] & 511], 1);
    __syncthreads();
    int node = b * 512 + tid;
    if (node < NN) cnt[node] = lc[tid];
    node += 256;
    if (node < NN) cnt[node] = lc[tid + 256];
}

__global__ void scanA_kernel(const int* __restrict__ cnt, int* __restrict__ bsum,
                             float* __restrict__ dinv) {
    __shared__ int sh[256];
    int tid = threadIdx.x;
    int base = blockIdx.x * 1024 + tid * 4;
    int s = 0;
#pragma unroll
    for (int i = 0; i < 4; ++i) {
        int idx = base + i;
        if (idx < NN) {
            int c = cnt[idx];
            s += c;
            dinv[idx] = rsqrtf(1.0f + (float)c);
        }
    }
    sh[tid] = s; __syncthreads();
    for (int d = 128; d > 0; d >>= 1) { if (tid < d) sh[tid] += sh[tid + d]; __syncthreads(); }
    if (tid == 0) bsum[blockIdx.x] = sh[0];
}

__global__ void scanB_kernel(int* __restrict__ bsum) {
    __shared__ int sh[128];
    int tid = threadIdx.x;
    int v = (tid < NB_SCAN) ? bsum[tid] : 0;
    sh[tid] = v; __syncthreads();
    for (int d = 1; d < 128; d <<= 1) {
        int t = (tid >= d) ? sh[tid - d] : 0;
        __syncthreads();
        sh[tid] += t;
        __syncthreads();
    }
    if (tid < NB_SCAN) bsum[tid] = sh[tid] - v;
}

__global__ void scanC_kernel(const int* __restrict__ cnt, const int* __restrict__ bsum,
                             int* __restrict__ row_ptr) {
    __shared__ int sh[256];
    int tid = threadIdx.x;
    int base = blockIdx.x * 1024 + tid * 4;
    int v[4];
#pragma unroll
    for (int i = 0; i < 4; ++i) { int idx = base + i; v[i] = (idx < NN) ? cnt[idx] : 0; }
    int tsum = v[0] + v[1] + v[2] + v[3];
    sh[tid] = tsum; __syncthreads();
    for (int d = 1; d < 256; d <<= 1) {
        int t = (tid >= d) ? sh[tid - d] : 0;
        __syncthreads();
        sh[tid] += t;
        __syncthreads();
    }
    int excl = sh[tid] - tsum + bsum[blockIdx.x];
#pragma unroll
    for (int i = 0; i < 4; ++i) {
        int idx = base + i;
        if (idx < NN) row_ptr[idx] = excl;
        excl += v[i];
    }
    if (blockIdx.x == 0 && tid == 0) row_ptr[NN] = EE;
}

__global__ __launch_bounds__(256) void cscatter_kernel(const int* __restrict__ bcur,
                                                       const int* __restrict__ bucket_edges,
                                                       const int* __restrict__ row_ptr,
                                                       const float* __restrict__ dinv,
                                                       int2* __restrict__ col) {
    __shared__ int lcur[512];
    int b = blockIdx.x, tid = threadIdx.x;
    int node0 = b * 512;
#pragma unroll
    for (int k = 0; k < 2; ++k) {
        int j = tid + k * 256;
        int node = node0 + j;
        if (node < NN) lcur[j] = row_ptr[node];
    }
    __syncthreads();
    int n = bcur[b];
    const int* be = bucket_edges + (size_t)b * BCAP;
    for (int i = tid; i < n; i += 256) {
        int w = be[i];
        int j = w & 511;
        int s = (int)((unsigned)w >> 9);
        int p = atomicAdd(&lcur[j], 1);
        float nm = dinv[s] * dinv[node0 + j];
        col[p] = make_int2(s, __float_as_int(nm));
    }
}

// ---------------- W^T hi/lo conversion ----------------
__global__ void wconv_kernel(const float* __restrict__ Ws,
                             unsigned short* __restrict__ WThi,
                             unsigned short* __restrict__ WTlo) {
    int id = blockIdx.x * 256 + threadIdx.x;
    if (id >= LL * HH * HH) return;
    int layer = id >> 14;
    int rem = id & (HH * HH - 1);
    int k = rem >> 7, n = rem & 127;
    float w = Ws[id];
    unsigned short hi = f2bf(w);
    float lo = w - bf2f(hi);
    WThi[(size_t)layer * HH * HH + n * HH + k] = hi;   // transposed: [n][k]
    WTlo[(size_t)layer * HH * HH + n * HH + k] = f2bf(lo);
}

// ---------------- Fused: atom encoder -> LDS -> MFMA @ W0 -> hw ----------------
__global__ __launch_bounds__(256) void enc_mm_kernel(const int* __restrict__ x,
        const float* __restrict__ emb,
        const unsigned short* __restrict__ WThi, const unsigned short* __restrict__ WTlo,
        __half* __restrict__ hw_out) {
    __shared__ __align__(16) unsigned short lh[32][136];
    __shared__ __align__(16) unsigned short ll[32][136];
    int tid = threadIdx.x;
    int nloc = tid >> 3;           // 0..31
    int seg = tid & 7;             // 16-ch segment
    int nodebase = blockIdx.x * 32;
    int n = nodebase + nloc;
    float s[16];
#pragma unroll
    for (int i = 0; i < 16; ++i) s[i] = 0.f;
#pragma unroll
    for (int f = 0; f < NF; ++f) {
        int idx = x[n * NF + f];
        const float4* ep = (const float4*)(emb + ((size_t)(f * VV + idx)) * HH + seg * 16);
#pragma unroll
        for (int q = 0; q < 4; ++q) {
            float4 e = ep[q];
            s[q * 4 + 0] += e.x; s[q * 4 + 1] += e.y;
            s[q * 4 + 2] += e.z; s[q * 4 + 3] += e.w;
        }
    }
#pragma unroll
    for (int q = 0; q < 4; ++q) {
        ushort4 oh, ol;
        oh.x = f2bf(s[q * 4 + 0]); ol.x = f2bf(s[q * 4 + 0] - bf2f(oh.x));
        oh.y = f2bf(s[q * 4 + 1]); ol.y = f2bf(s[q * 4 + 1] - bf2f(oh.y));
        oh.z = f2bf(s[q * 4 + 2]); ol.z = f2bf(s[q * 4 + 2] - bf2f(oh.z));
        oh.w = f2bf(s[q * 4 + 3]); ol.w = f2bf(s[q * 4 + 3] - bf2f(oh.w));
        *(ushort4*)&lh[nloc][seg * 16 + q * 4] = oh;
        *(ushort4*)&ll[nloc][seg * 16 + q * 4] = ol;
    }
    __syncthreads();
    int wave = tid >> 6, lane = tid & 63;
    int quad = lane >> 4, m = lane & 15;
    f32x4 acc[2][2] = {};
    int kq = quad * 8;
#pragma unroll
    for (int t = 0; t < 4; ++t) {
        int k0 = t * 32 + kq;
        short8 a0h = *(const short8*)&lh[m][k0];
        short8 a0l = *(const short8*)&ll[m][k0];
        short8 a1h = *(const short8*)&lh[16 + m][k0];
        short8 a1l = *(const short8*)&ll[16 + m][k0];
#pragma unroll
        for (int c = 0; c < 2; ++c) {
            int ct = wave * 2 + c;
            short8 bh = *(const short8*)(WThi + (size_t)(ct * 16 + m) * HH + k0);
            short8 bl = *(const short8*)(WTlo + (size_t)(ct * 16 + m) * HH + k0);
            acc[0][c] = __builtin_amdgcn_mfma_f32_16x16x32_bf16(a0h, bh, acc[0][c], 0, 0, 0);
            acc[0][c] = __builtin_amdgcn_mfma_f32_16x16x32_bf16(a0l, bh, acc[0][c], 0, 0, 0);
            acc[0][c] = __builtin_amdgcn_mfma_f32_16x16x32_bf16(a0h, bl, acc[0][c], 0, 0, 0);
            acc[1][c] = __builtin_amdgcn_mfma_f32_16x16x32_bf16(a1h, bh, acc[1][c], 0, 0, 0);
            acc[1][c] = __builtin_amdgcn_mfma_f32_16x16x32_bf16(a1l, bh, acc[1][c], 0, 0, 0);
            acc[1][c] = __builtin_amdgcn_mfma_f32_16x16x32_bf16(a1h, bl, acc[1][c], 0, 0, 0);
        }
    }
#pragma unroll
    for (int c = 0; c < 2; ++c) {
        int colx = (wave * 2 + c) * 16 + m;
#pragma unroll
        for (int rt = 0; rt < 2; ++rt) {
            int r0 = nodebase + rt * 16 + quad * 4;
#pragma unroll
            for (int reg = 0; reg < 4; ++reg)
                hw_out[(size_t)(r0 + reg) * HH + colx] = __float2half(acc[rt][c][reg]);
        }
    }
}

// ---------------- Fused: CSR aggregate + bias + BN + ReLU -> LDS -> MFMA @ Wnext ----------------
// 512 threads = 8 waves x 4 nodes (short chains, 32 waves/CU for MLP); MFMA tail 1 ct/wave.
__global__ __launch_bounds__(512) void agg_mm_kernel(const __half* __restrict__ hw_in,
    const int* __restrict__ row_ptr, const int2* __restrict__ col,
    const float* __restrict__ dinv,
    const float* __restrict__ bias, const float* __restrict__ gamma,
    const float* __restrict__ beta, const float* __restrict__ rmean,
    const float* __restrict__ rvar,
    const unsigned short* __restrict__ WThi, const unsigned short* __restrict__ WTlo,
    __half* __restrict__ hw_out) {
    __shared__ __align__(16) unsigned short lh[32][136];
    __shared__ __align__(16) unsigned short ll[32][136];
    int wave = threadIdx.x >> 6;     // 0..7
    int lane = threadIdx.x & 63;
    int grp = lane >> 4;             // 0..3
    int c4 = lane & 15;
    int nodebase = blockIdx.x * 32;
    const uint4* hw4 = (const uint4*)hw_in;

    for (int nn = 0; nn < 4; ++nn) {
        int v = nodebase + wave * 4 + nn;
        int start = row_ptr[v], end = row_ptr[v + 1];
        float a[8] = {}, b[8] = {};
        for (int j0 = start; j0 < end; j0 += 64) {
            int jj = j0 + lane;
            int sp = 0; float np = 0.f;
            if (jj < end) {
                unsigned long long w = __builtin_nontemporal_load((const unsigned long long*)&col[jj]);
                sp = (int)(unsigned)(w & 0xffffffffu);
                np = __int_as_float((int)(unsigned)(w >> 32));
            }
            int rem = min(64, end - j0);
            int iters = (rem + 3) >> 2;
            int it = 0;
            for (; it + 2 <= iters; it += 2) {
                int i0 = it * 4 + grp, i1 = i0 + 4;
                int s0 = __shfl(sp, i0), s1 = __shfl(sp, i1);
                float n0 = __shfl(np, i0), n1 = __shfl(np, i1);
                uint4 r0 = hw4[(size_t)s0 * 16 + c4];
                uint4 r1 = hw4[(size_t)s1 * 16 + c4];
                mix8(a, r0, n0);
                mix8(b, r1, n1);
            }
            if (it < iters) {
                int i0 = it * 4 + grp;
                int s0 = __shfl(sp, i0);
                float n0 = __shfl(np, i0);
                uint4 r0 = hw4[(size_t)s0 * 16 + c4];
                mix8(a, r0, n0);
            }
        }
#pragma unroll
        for (int i = 0; i < 8; ++i) a[i] += b[i];
#pragma unroll
        for (int mlt = 16; mlt <= 32; mlt <<= 1) {
#pragma unroll
            for (int i = 0; i < 8; ++i) a[i] += __shfl_xor(a[i], mlt);
        }
        if (grp == 0) {
            int ch = c4 * 8;
            float dv = dinv[v];
            float ns = dv * dv;
            uint4 r = hw4[(size_t)v * 16 + c4];
            mix8(a, r, ns);
#pragma unroll
            for (int i = 0; i < 8; ++i) a[i] += bias[ch + i];
#pragma unroll
            for (int i = 0; i < 8; ++i) {
                int c = ch + i;
                float sc = gamma[c] * rsqrtf(rvar[c] + BN_EPS);
                a[i] = fmaxf((a[i] - rmean[c]) * sc + beta[c], 0.f);
            }
            int rloc = wave * 4 + nn;
            ushort4 oh0, oh1, ol0, ol1;
            oh0.x = f2bf(a[0]); ol0.x = f2bf(a[0] - bf2f(oh0.x));
            oh0.y = f2bf(a[1]); ol0.y = f2bf(a[1] - bf2f(oh0.y));
            oh0.z = f2bf(a[2]); ol0.z = f2bf(a[2] - bf2f(oh0.z));
            oh0.w = f2bf(a[3]); ol0.w = f2bf(a[3] - bf2f(oh0.w));
            oh1.x = f2bf(a[4]); ol1.x = f2bf(a[4] - bf2f(oh1.x));
            oh1.y = f2bf(a[5]); ol1.y = f2bf(a[5] - bf2f(oh1.y));
            oh1.z = f2bf(a[6]); ol1.z = f2bf(a[6] - bf2f(oh1.z));
            oh1.w = f2bf(a[7]); ol1.w = f2bf(a[7] - bf2f(oh1.w));
            *(ushort4*)&lh[rloc][ch]     = oh0;
            *(ushort4*)&lh[rloc][ch + 4] = oh1;
            *(ushort4*)&ll[rloc][ch]     = ol0;
            *(ushort4*)&ll[rloc][ch + 4] = ol1;
        }
    }
    __syncthreads();
    int quad = lane >> 4, m = lane & 15;
    f32x4 acc[2] = {};
    int kq = quad * 8;
    int ct = wave;                   // 1 column-tile per wave
#pragma unroll
    for (int t = 0; t < 4; ++t) {
        int k0 = t * 32 + kq;
        short8 a0h = *(const short8*)&lh[m][k0];
        short8 a0l = *(const short8*)&ll[m][k0];
        short8 a1h = *(const short8*)&lh[16 + m][k0];
        short8 a1l = *(const short8*)&ll[16 + m][k0];
        short8 bh = *(const short8*)(WThi + (size_t)(ct * 16 + m) * HH + k0);
        short8 bl = *(const short8*)(WTlo + (size_t)(ct * 16 + m) * HH + k0);
        acc[0] = __builtin_amdgcn_mfma_f32_16x16x32_bf16(a0h, bh, acc[0], 0, 0, 0);
        acc[0] = __builtin_amdgcn_mfma_f32_16x16x32_bf16(a0l, bh, acc[0], 0, 0, 0);
        acc[0] = __builtin_amdgcn_mfma_f32_16x16x32_bf16(a0h, bl, acc[0], 0, 0, 0);
        acc[1] = __builtin_amdgcn_mfma_f32_16x16x32_bf16(a1h, bh, acc[1], 0, 0, 0);
        acc[1] = __builtin_amdgcn_mfma_f32_16x16x32_bf16(a1l, bh, acc[1], 0, 0, 0);
        acc[1] = __builtin_amdgcn_mfma_f32_16x16x32_bf16(a1h, bl, acc[1], 0, 0, 0);
    }
    int colx = ct * 16 + m;
#pragma unroll
    for (int rt = 0; rt < 2; ++rt) {
        int r0 = nodebase + rt * 16 + quad * 4;
#pragma unroll
        for (int reg = 0; reg < 4; ++reg)
            hw_out[(size_t)(r0 + reg) * HH + colx] = __float2half(acc[rt][reg]);
    }
}

// ---------------- Fused: last aggregate (bias only) + per-graph pooling partials ----------------
__global__ __launch_bounds__(512) void agg_pool_kernel(const __half* __restrict__ hw_in,
    const int* __restrict__ row_ptr, const int2* __restrict__ col,
    const float* __restrict__ dinv, const float* __restrict__ bias,
    const int* __restrict__ batch, float* __restrict__ pooled) {
    __shared__ __align__(16) float lf[32][132];
    __shared__ int bg[32];
    int wave = threadIdx.x >> 6;
    int lane = threadIdx.x & 63;
    int grp = lane >> 4;
    int c4 = lane & 15;
    int nodebase = blockIdx.x * 32;
    const uint4* hw4 = (const uint4*)hw_in;

    for (int nn = 0; nn < 4; ++nn) {
        int v = nodebase + wave * 4 + nn;
        int start = row_ptr[v], end = row_ptr[v + 1];
        float a[8] = {}, b[8] = {};
        for (int j0 = start; j0 < end; j0 += 64) {
            int jj = j0 + lane;
            int sp = 0; float np = 0.f;
            if (jj < end) {
                unsigned long long w = __builtin_nontemporal_load((const unsigned long long*)&col[jj]);
                sp = (int)(unsigned)(w & 0xffffffffu);
                np = __int_as_float((int)(unsigned)(w >> 32));
            }
            int rem = min(64, end - j0);
            int iters = (rem + 3) >> 2;
            int it = 0;
            for (; it + 2 <= iters; it += 2) {
                int i0 = it * 4 + grp, i1 = i0 + 4;
                int s0 = __shfl(sp, i0), s1 = __shfl(sp, i1);
                float n0 = __shfl(np, i0), n1 = __shfl(np, i1);
                uint4 r0 = hw4[(size_t)s0 * 16 + c4];
                uint4 r1 = hw4[(size_t)s1 * 16 + c4];
                mix8(a, r0, n0);
                mix8(b, r1, n1);
            }
            if (it < iters) {
                int i0 = it * 4 + grp;
                int s0 = __shfl(sp, i0);
                float n0 = __shfl(np, i0);
                uint4 r0 = hw4[(size_t)s0 * 16 + c4];
                mix8(a, r0, n0);
            }
        }
#pragma unroll
        for (int i = 0; i < 8; ++i) a[i] += b[i];
#pragma unroll
        for (int mlt = 16; mlt <= 32; mlt <<= 1) {
#pragma unroll
            for (int i = 0; i < 8; ++i) a[i] += __shfl_xor(a[i], mlt);
        }
        if (grp == 0) {
            int ch = c4 * 8;
            float dv = dinv[v];
            float ns = dv * dv;
            uint4 r = hw4[(size_t)v * 16 + c4];
            mix8(a, r, ns);
            int rloc = wave * 4 + nn;
#pragma unroll
            for (int i = 0; i < 8; ++i) lf[rloc][ch + i] = a[i] + bias[ch + i];
            if (c4 == 0) bg[rloc] = batch[v];
        }
    }
    __syncthreads();
    // pooling partials: 512 threads = 128 ch x 4 row-groups of 8
    int c = threadIdx.x & 127;
    int rh = threadIdx.x >> 7;       // 0..3
    int r0 = rh * 8;
    int curg = bg[r0];
    float run = 0.f;
    for (int r = r0; r < r0 + 8; ++r) {
        int gg = bg[r];
        if (gg != curg) {
            atomicAdd(&pooled[(size_t)curg * HH + c], run);
            run = 0.f; curg = gg;
        }
        run += lf[r][c];
    }
    atomicAdd(&pooled[(size_t)curg * HH + c], run);
}

// ---------------- mean + classifier ----------------
__global__ __launch_bounds__(128) void clf_kernel(const float* __restrict__ pooled,
    const int* __restrict__ batch, const float* __restrict__ Wc,
    const float* __restrict__ bc, float* __restrict__ out) {
    __shared__ float pl[HH];
    int g = blockIdx.x;
    int tid = threadIdx.x;
    int lo = 0, hi = NN;
    while (lo < hi) { int mid = (lo + hi) >> 1; if (batch[mid] < g) lo = mid + 1; else hi = mid; }
    int start = lo;
    lo = 0; hi = NN;
    int g1 = g + 1;
    while (lo < hi) { int mid = (lo + hi) >> 1; if (batch[mid] < g1) lo = mid + 1; else hi = mid; }
    float cnt = (float)(lo - start);
    pl[tid] = pooled[(size_t)g * HH + tid] / fmaxf(cnt, 1.0f);
    __syncthreads();
    if (tid < OUTD) {
        float acc = bc[tid];
#pragma unroll 16
        for (int c = 0; c < HH; ++c) acc += pl[c] * Wc[c * OUTD + tid];
        out[g * OUTD + tid] = acc;
    }
}

extern "C" void kernel_launch(void* const* d_in, const int* in_sizes, int n_in,
                              void* d_out, int out_size, void* d_ws, size_t ws_size,
                              hipStream_t stream) {
    const int*   x      = (const int*)d_in[0];
    const int*   eidx   = (const int*)d_in[1];
    const int*   batch  = (const int*)d_in[2];
    const float* emb    = (const float*)d_in[3];
    const float* Ws     = (const float*)d_in[4];
    const float* bs     = (const float*)d_in[5];
    const float* gamma  = (const float*)d_in[6];
    const float* beta   = (const float*)d_in[7];
    const float* rmean  = (const float*)d_in[8];
    const float* rvar   = (const float*)d_in[9];
    const float* Wclf   = (const float*)d_in[10];
    const float* bclf   = (const float*)d_in[11];
    float* out = (float*)d_out;

    const int* e_src = eidx;
    const int* e_dst = eidx + EE;

    char* ws = (char*)d_ws;
    size_t off = 0;
    auto take = [&](size_t bytes) -> void* {
        void* p = ws + off;
        off = (off + bytes + 255) & ~(size_t)255;
        return p;
    };
    float* dinv     = (float*)take((size_t)NN * 4);
    int*   cnt      = (int*)  take((size_t)NN * 4);
    int*   row_ptr  = (int*)  take((size_t)(NN + 1) * 4);
    int*   bsum     = (int*)  take((size_t)NB_SCAN * 4);
    int*   bcur     = (int*)  take((size_t)256 * 4);
    int*   bucket_edges = (int*)take((size_t)NBUCK * BCAP * 4);
    int2*  col      = (int2*) take((size_t)EE * 8);
    __half* hwA     = (__half*)take((size_t)NN * HH * 2);
    __half* hwB     = (__half*)take((size_t)NN * HH * 2);
    float* pooled   = (float*)take((size_t)GG * HH * 4);
    unsigned short* WThi = (unsigned short*)take((size_t)LL * HH * HH * 2);
    unsigned short* WTlo = (unsigned short*)take((size_t)LL * HH * HH * 2);

    hipMemsetAsync(bcur, 0, 256 * 4, stream);
    hipMemsetAsync(pooled, 0, (size_t)GG * HH * 4, stream);

    split_kernel<<<(EE + CHUNK - 1) / CHUNK, 256, 0, stream>>>(e_src, e_dst, bcur, bucket_edges);
    bhist_kernel<<<NBUCK, 256, 0, stream>>>(bcur, bucket_edges, cnt);
    scanA_kernel<<<NB_SCAN, 256, 0, stream>>>(cnt, bsum, dinv);
    scanB_kernel<<<1, 128, 0, stream>>>(bsum);
    scanC_kernel<<<NB_SCAN, 256, 0, stream>>>(cnt, bsum, row_ptr);
    cscatter_kernel<<<NBUCK, 256, 0, stream>>>(bcur, bucket_edges, row_ptr, dinv, col);
    wconv_kernel<<<(LL * HH * HH + 255) / 256, 256, 0, stream>>>(Ws, WThi, WTlo);

    // encoder -> LDS -> @ W0 -> hw1
    enc_mm_kernel<<<NN / 32, 256, 0, stream>>>(x, emb, WThi, WTlo, hwA);
    // layer 0: agg(hw1)+bias0+BN0+ReLU -> LDS -> @ W1 -> hw2
    agg_mm_kernel<<<NN / 32, 512, 0, stream>>>(hwA, row_ptr, col, dinv,
        bs, gamma, beta, rmean, rvar,
        WThi + (size_t)1 * HH * HH, WTlo + (size_t)1 * HH * HH, hwB);
    // layer 1: agg(hw2)+bias1+BN1+ReLU -> LDS -> @ W2 -> hw3
    agg_mm_kernel<<<NN / 32, 512, 0, stream>>>(hwB, row_ptr, col, dinv,
        bs + HH, gamma + HH, beta + HH, rmean + HH, rvar + HH,
        WThi + (size_t)2 * HH * HH, WTlo + (size_t)2 * HH * HH, hwA);
    // layer 2: agg(hw3)+bias2 -> pooling partials
    agg_pool_kernel<<<NN / 32, 512, 0, stream>>>(hwA, row_ptr, col, dinv,
        bs + 2 * HH, batch, pooled);

    clf_kernel<<<GG, 128, 0, stream>>>(pooled, batch, Wclf, bclf, out);
}

// Round 13
// 484.210 us; speedup vs baseline: 1.0868x; 1.0001x over previous
//
#include <hip/hip_runtime.h>
#include <hip/hip_bf16.h>
#include <hip/hip_fp16.h>

#define NN 100000      // nodes
#define EE 1600000     // edges
#define GG 1024        // graphs
#define NF 9
#define VV 128
#define HH 128
#define LL 3
#define OUTD 10
#define BN_EPS 1e-5f
#define NB_SCAN 98     // ceil(NN/1024)
#define NBUCK 196      // ceil(NN/512) buckets of 512 nodes
#define BCAP 12288     // bucket capacity (avg fill 8192)
#define CHUNK 4096     // edges per split block

typedef __attribute__((ext_vector_type(8))) short short8;   // 8 bf16 = 4 VGPRs
typedef __attribute__((ext_vector_type(4))) float f32x4;

__device__ inline unsigned short f2bf(float x) {          // RNE f32 -> bf16 bits
    unsigned u = __float_as_uint(x);
    unsigned r = (u + 0x7fffu + ((u >> 16) & 1u)) >> 16;
    return (unsigned short)r;
}
__device__ inline float bf2f(unsigned short b) { return __uint_as_float(((unsigned)b) << 16); }

// 8x v_fma_mix_f32: a[i] += f32(half_i(r)) * nm   (bit-identical to cvt+fmaf)
__device__ inline void mix8(float a[8], const uint4& r, float nm) {
    asm("v_fma_mix_f32 %0, %8, %12, %0 op_sel:[0,0,0] op_sel_hi:[1,0,0]\n\t"
        "v_fma_mix_f32 %1, %8, %12, %1 op_sel:[1,0,0] op_sel_hi:[1,0,0]\n\t"
        "v_fma_mix_f32 %2, %9, %12, %2 op_sel:[0,0,0] op_sel_hi:[1,0,0]\n\t"
        "v_fma_mix_f32 %3, %9, %12, %3 op_sel:[1,0,0] op_sel_hi:[1,0,0]\n\t"
        "v_fma_mix_f32 %4, %10, %12, %4 op_sel:[0,0,0] op_sel_hi:[1,0,0]\n\t"
        "v_fma_mix_f32 %5, %10, %12, %5 op_sel:[1,0,0] op_sel_hi:[1,0,0]\n\t"
        "v_fma_mix_f32 %6, %11, %12, %6 op_sel:[0,0,0] op_sel_hi:[1,0,0]\n\t"
        "v_fma_mix_f32 %7, %11, %12, %7 op_sel:[1,0,0] op_sel_hi:[1,0,0]"
        : "+v"(a[0]), "+v"(a[1]), "+v"(a[2]), "+v"(a[3]),
          "+v"(a[4]), "+v"(a[5]), "+v"(a[6]), "+v"(a[7])
        : "v"(r.x), "v"(r.y), "v"(r.z), "v"(r.w), "v"(nm));
}

// ---------------- Two-level CSR build ----------------
__global__ __launch_bounds__(256) void split_kernel(const int* __restrict__ src,
                                                    const int* __restrict__ dst,
                                                    int* __restrict__ bcur,
                                                    int* __restrict__ bucket_edges) {
    __shared__ int lcnt[256], loff[256], lcur[256], gbase[256], sh[256];
    __shared__ int stage[CHUNK];
    __shared__ unsigned char stageb[CHUNK];
    int tid = threadIdx.x;
    int cs = blockIdx.x * CHUNK;
    int n = min(CHUNK, EE - cs);
    lcnt[tid] = 0;
    __syncthreads();
    for (int i = tid; i < n; i += 256)
        atomicAdd(&lcnt[dst[cs + i] >> 9], 1);
    __syncthreads();
    int val = lcnt[tid];
    sh[tid] = val; __syncthreads();
    for (int d = 1; d < 256; d <<= 1) {
        int t = (tid >= d) ? sh[tid - d] : 0;
        __syncthreads();
        sh[tid] += t;
        __syncthreads();
    }
    loff[tid] = sh[tid] - val;
    lcur[tid] = sh[tid] - val;
    __syncthreads();
    for (int i = tid; i < n; i += 256) {
        int d = dst[cs + i], s = src[cs + i];
        int b = d >> 9;
        int p = atomicAdd(&lcur[b], 1);
        stage[p] = (s << 9) | (d & 511);
        stageb[p] = (unsigned char)b;
    }
    if (val > 0) gbase[tid] = atomicAdd(&bcur[tid], val);
    __syncthreads();
    for (int i = tid; i < n; i += 256) {
        int b = stageb[i];
        bucket_edges[(size_t)b * BCAP + gbase[b] + (i - loff[b])] = stage[i];
    }
}

__global__ __launch_bounds__(256) void bhist_kernel(const int* __restrict__ bcur,
                                                    const int* __restrict__ bucket_edges,
                                                    int* __restrict__ cnt) {
    __shared__ int lc[512];
    int b = blockIdx.x, tid = threadIdx.x;
    lc[tid] = 0; lc[tid + 256] = 0;
    __syncthreads();
    int n = bcur[b];
    const int* be = bucket_edges + (size_t)b * BCAP;
    for (int i = tid; i < n; i += 256) atomicAdd(&lc[be[i] & 511], 1);
    __syncthreads();
    int node = b * 512 + tid;
    if (node < NN) cnt[node] = lc[tid];
    node += 256;
    if (node < NN) cnt[node] = lc[tid + 256];
}

__global__ void scanA_kernel(const int* __restrict__ cnt, int* __restrict__ bsum,
                             float* __restrict__ dinv) {
    __shared__ int sh[256];
    int tid = threadIdx.x;
    int base = blockIdx.x * 1024 + tid * 4;
    int s = 0;
#pragma unroll
    for (int i = 0; i < 4; ++i) {
        int idx = base + i;
        if (idx < NN) {
            int c = cnt[idx];
            s += c;
            dinv[idx] = rsqrtf(1.0f + (float)c);
        }
    }
    sh[tid] = s; __syncthreads();
    for (int d = 128; d > 0; d >>= 1) { if (tid < d) sh[tid] += sh[tid + d]; __syncthreads(); }
    if (tid == 0) bsum[blockIdx.x] = sh[0];
}

__global__ void scanB_kernel(int* __restrict__ bsum) {
    __shared__ int sh[128];
    int tid = threadIdx.x;
    int v = (tid < NB_SCAN) ? bsum[tid] : 0;
    sh[tid] = v; __syncthreads();
    for (int d = 1; d < 128; d <<= 1) {
        int t = (tid >= d) ? sh[tid - d] : 0;
        __syncthreads();
        sh[tid] += t;
        __syncthreads();
    }
    if (tid < NB_SCAN) bsum[tid] = sh[tid] - v;
}

__global__ void scanC_kernel(const int* __restrict__ cnt, const int* __restrict__ bsum,
                             int* __restrict__ row_ptr) {
    __shared__ int sh[256];
    int tid = threadIdx.x;
    int base = blockIdx.x * 1024 + tid * 4;
    int v[4];
#pragma unroll
    for (int i = 0; i < 4; ++i) { int idx = base + i; v[i] = (idx < NN) ? cnt[idx] : 0; }
    int tsum = v[0] + v[1] + v[2] + v[3];
    sh[tid] = tsum; __syncthreads();
    for (int d = 1; d < 256; d <<= 1) {
        int t = (tid >= d) ? sh[tid - d] : 0;
        __syncthreads();
        sh[tid] += t;
        __syncthreads();
    }
    int excl = sh[tid] - tsum + bsum[blockIdx.x];
#pragma unroll
    for (int i = 0; i < 4; ++i) {
        int idx = base + i;
        if (idx < NN) row_ptr[idx] = excl;
        excl += v[i];
    }
    if (blockIdx.x == 0 && tid == 0) row_ptr[NN] = EE;
}

__global__ __launch_bounds__(256) void cscatter_kernel(const int* __restrict__ bcur,
                                                       const int* __restrict__ bucket_edges,
                                                       const int* __restrict__ row_ptr,
                                                       const float* __restrict__ dinv,
                                                       int2* __restrict__ col) {
    __shared__ int lcur[512];
    int b = blockIdx.x, tid = threadIdx.x;
    int node0 = b * 512;
#pragma unroll
    for (int k = 0; k < 2; ++k) {
        int j = tid + k * 256;
        int node = node0 + j;
        if (node < NN) lcur[j] = row_ptr[node];
    }
    __syncthreads();
    int n = bcur[b];
    const int* be = bucket_edges + (size_t)b * BCAP;
    for (int i = tid; i < n; i += 256) {
        int w = be[i];
        int j = w & 511;
        int s = (int)((unsigned)w >> 9);
        int p = atomicAdd(&lcur[j], 1);
        float nm = dinv[s] * dinv[node0 + j];
        col[p] = make_int2(s, __float_as_int(nm));
    }
}

// ---------------- W^T hi/lo conversion ----------------
__global__ void wconv_kernel(const float* __restrict__ Ws,
                             unsigned short* __restrict__ WThi,
                             unsigned short* __restrict__ WTlo) {
    int id = blockIdx.x * 256 + threadIdx.x;
    if (id >= LL * HH * HH) return;
    int layer = id >> 14;
    int rem = id & (HH * HH - 1);
    int k = rem >> 7, n = rem & 127;
    float w = Ws[id];
    unsigned short hi = f2bf(w);
    float lo = w - bf2f(hi);
    WThi[(size_t)layer * HH * HH + n * HH + k] = hi;   // transposed: [n][k]
    WTlo[(size_t)layer * HH * HH + n * HH + k] = f2bf(lo);
}

// ---------------- Fused: atom encoder -> LDS -> MFMA @ W0 -> hw ----------------
__global__ __launch_bounds__(256) void enc_mm_kernel(const int* __restrict__ x,
        const float* __restrict__ emb,
        const unsigned short* __restrict__ WThi, const unsigned short* __restrict__ WTlo,
        __half* __restrict__ hw_out) {
    __shared__ __align__(16) unsigned short lh[32][136];
    __shared__ __align__(16) unsigned short ll[32][136];
    int tid = threadIdx.x;
    int nloc = tid >> 3;           // 0..31
    int seg = tid & 7;             // 16-ch segment
    int nodebase = blockIdx.x * 32;
    int n = nodebase + nloc;
    float s[16];
#pragma unroll
    for (int i = 0; i < 16; ++i) s[i] = 0.f;
#pragma unroll
    for (int f = 0; f < NF; ++f) {
        int idx = x[n * NF + f];
        const float4* ep = (const float4*)(emb + ((size_t)(f * VV + idx)) * HH + seg * 16);
#pragma unroll
        for (int q = 0; q < 4; ++q) {
            float4 e = ep[q];
            s[q * 4 + 0] += e.x; s[q * 4 + 1] += e.y;
            s[q * 4 + 2] += e.z; s[q * 4 + 3] += e.w;
        }
    }
#pragma unroll
    for (int q = 0; q < 4; ++q) {
        ushort4 oh, ol;
        oh.x = f2bf(s[q * 4 + 0]); ol.x = f2bf(s[q * 4 + 0] - bf2f(oh.x));
        oh.y = f2bf(s[q * 4 + 1]); ol.y = f2bf(s[q * 4 + 1] - bf2f(oh.y));
        oh.z = f2bf(s[q * 4 + 2]); ol.z = f2bf(s[q * 4 + 2] - bf2f(oh.z));
        oh.w = f2bf(s[q * 4 + 3]); ol.w = f2bf(s[q * 4 + 3] - bf2f(oh.w));
        *(ushort4*)&lh[nloc][seg * 16 + q * 4] = oh;
        *(ushort4*)&ll[nloc][seg * 16 + q * 4] = ol;
    }
    __syncthreads();
    int wave = tid >> 6, lane = tid & 63;
    int quad = lane >> 4, m = lane & 15;
    f32x4 acc[2][2] = {};
    int kq = quad * 8;
#pragma unroll
    for (int t = 0; t < 4; ++t) {
        int k0 = t * 32 + kq;
        short8 a0h = *(const short8*)&lh[m][k0];
        short8 a0l = *(const short8*)&ll[m][k0];
        short8 a1h = *(const short8*)&lh[16 + m][k0];
        short8 a1l = *(const short8*)&ll[16 + m][k0];
#pragma unroll
        for (int c = 0; c < 2; ++c) {
            int ct = wave * 2 + c;
            short8 bh = *(const short8*)(WThi + (size_t)(ct * 16 + m) * HH + k0);
            short8 bl = *(const short8*)(WTlo + (size_t)(ct * 16 + m) * HH + k0);
            acc[0][c] = __builtin_amdgcn_mfma_f32_16x16x32_bf16(a0h, bh, acc[0][c], 0, 0, 0);
            acc[0][c] = __builtin_amdgcn_mfma_f32_16x16x32_bf16(a0l, bh, acc[0][c], 0, 0, 0);
            acc[0][c] = __builtin_amdgcn_mfma_f32_16x16x32_bf16(a0h, bl, acc[0][c], 0, 0, 0);
            acc[1][c] = __builtin_amdgcn_mfma_f32_16x16x32_bf16(a1h, bh, acc[1][c], 0, 0, 0);
            acc[1][c] = __builtin_amdgcn_mfma_f32_16x16x32_bf16(a1l, bh, acc[1][c], 0, 0, 0);
            acc[1][c] = __builtin_amdgcn_mfma_f32_16x16x32_bf16(a1h, bl, acc[1][c], 0, 0, 0);
        }
    }
#pragma unroll
    for (int c = 0; c < 2; ++c) {
        int colx = (wave * 2 + c) * 16 + m;
#pragma unroll
        for (int rt = 0; rt < 2; ++rt) {
            int r0 = nodebase + rt * 16 + quad * 4;
#pragma unroll
            for (int reg = 0; reg < 4; ++reg)
                hw_out[(size_t)(r0 + reg) * HH + colx] = __float2half(acc[rt][c][reg]);
        }
    }
}

// ---------------- Fused: CSR aggregate + bias + BN + ReLU -> LDS -> MFMA @ Wnext ----------------
// 512 threads = 8 waves x 4 nodes. Gather: 4 row-loads issued before first consume
// (4 misses in flight per lane-group), 2 accumulator sets.
__global__ __launch_bounds__(512) void agg_mm_kernel(const __half* __restrict__ hw_in,
    const int* __restrict__ row_ptr, const int2* __restrict__ col,
    const float* __restrict__ dinv,
    const float* __restrict__ bias, const float* __restrict__ gamma,
    const float* __restrict__ beta, const float* __restrict__ rmean,
    const float* __restrict__ rvar,
    const unsigned short* __restrict__ WThi, const unsigned short* __restrict__ WTlo,
    __half* __restrict__ hw_out) {
    __shared__ __align__(16) unsigned short lh[32][136];
    __shared__ __align__(16) unsigned short ll[32][136];
    int wave = threadIdx.x >> 6;     // 0..7
    int lane = threadIdx.x & 63;
    int grp = lane >> 4;             // 0..3
    int c4 = lane & 15;
    int nodebase = blockIdx.x * 32;
    const uint4* hw4 = (const uint4*)hw_in;

    for (int nn = 0; nn < 4; ++nn) {
        int v = nodebase + wave * 4 + nn;
        int start = row_ptr[v], end = row_ptr[v + 1];
        float a[8] = {}, b[8] = {};
        for (int j0 = start; j0 < end; j0 += 64) {
            int jj = j0 + lane;
            int sp = 0; float np = 0.f;
            if (jj < end) {
                unsigned long long w = __builtin_nontemporal_load((const unsigned long long*)&col[jj]);
                sp = (int)(unsigned)(w & 0xffffffffu);
                np = __int_as_float((int)(unsigned)(w >> 32));
            }
            int rem = min(64, end - j0);
            int iters = (rem + 3) >> 2;
            int it = 0;
            for (; it + 4 <= iters; it += 4) {
                int i0 = it * 4 + grp;
                int s0 = __shfl(sp, i0),      s1 = __shfl(sp, i0 + 4);
                int s2 = __shfl(sp, i0 + 8),  s3 = __shfl(sp, i0 + 12);
                float n0 = __shfl(np, i0),     n1 = __shfl(np, i0 + 4);
                float n2 = __shfl(np, i0 + 8), n3 = __shfl(np, i0 + 12);
                uint4 r0 = hw4[(size_t)s0 * 16 + c4];
                uint4 r1 = hw4[(size_t)s1 * 16 + c4];
                uint4 r2 = hw4[(size_t)s2 * 16 + c4];
                uint4 r3 = hw4[(size_t)s3 * 16 + c4];
                mix8(a, r0, n0);
                mix8(b, r1, n1);
                mix8(a, r2, n2);
                mix8(b, r3, n3);
            }
            for (; it + 2 <= iters; it += 2) {
                int i0 = it * 4 + grp, i1 = i0 + 4;
                int s0 = __shfl(sp, i0), s1 = __shfl(sp, i1);
                float n0 = __shfl(np, i0), n1 = __shfl(np, i1);
                uint4 r0 = hw4[(size_t)s0 * 16 + c4];
                uint4 r1 = hw4[(size_t)s1 * 16 + c4];
                mix8(a, r0, n0);
                mix8(b, r1, n1);
            }
            if (it < iters) {
                int i0 = it * 4 + grp;
                int s0 = __shfl(sp, i0);
                float n0 = __shfl(np, i0);
                uint4 r0 = hw4[(size_t)s0 * 16 + c4];
                mix8(a, r0, n0);
            }
        }
#pragma unroll
        for (int i = 0; i < 8; ++i) a[i] += b[i];
#pragma unroll
        for (int mlt = 16; mlt <= 32; mlt <<= 1) {
#pragma unroll
            for (int i = 0; i < 8; ++i) a[i] += __shfl_xor(a[i], mlt);
        }
        if (grp == 0) {
            int ch = c4 * 8;
            float dv = dinv[v];
            float ns = dv * dv;
            uint4 r = hw4[(size_t)v * 16 + c4];
            mix8(a, r, ns);
#pragma unroll
            for (int i = 0; i < 8; ++i) a[i] += bias[ch + i];
#pragma unroll
            for (int i = 0; i < 8; ++i) {
                int c = ch + i;
                float sc = gamma[c] * rsqrtf(rvar[c] + BN_EPS);
                a[i] = fmaxf((a[i] - rmean[c]) * sc + beta[c], 0.f);
            }
            int rloc = wave * 4 + nn;
            ushort4 oh0, oh1, ol0, ol1;
            oh0.x = f2bf(a[0]); ol0.x = f2bf(a[0] - bf2f(oh0.x));
            oh0.y = f2bf(a[1]); ol0.y = f2bf(a[1] - bf2f(oh0.y));
            oh0.z = f2bf(a[2]); ol0.z = f2bf(a[2] - bf2f(oh0.z));
            oh0.w = f2bf(a[3]); ol0.w = f2bf(a[3] - bf2f(oh0.w));
            oh1.x = f2bf(a[4]); ol1.x = f2bf(a[4] - bf2f(oh1.x));
            oh1.y = f2bf(a[5]); ol1.y = f2bf(a[5] - bf2f(oh1.y));
            oh1.z = f2bf(a[6]); ol1.z = f2bf(a[6] - bf2f(oh1.z));
            oh1.w = f2bf(a[7]); ol1.w = f2bf(a[7] - bf2f(oh1.w));
            *(ushort4*)&lh[rloc][ch]     = oh0;
            *(ushort4*)&lh[rloc][ch + 4] = oh1;
            *(ushort4*)&ll[rloc][ch]     = ol0;
            *(ushort4*)&ll[rloc][ch + 4] = ol1;
        }
    }
    __syncthreads();
    int quad = lane >> 4, m = lane & 15;
    f32x4 acc[2] = {};
    int kq = quad * 8;
    int ct = wave;                   // 1 column-tile per wave
#pragma unroll
    for (int t = 0; t < 4; ++t) {
        int k0 = t * 32 + kq;
        short8 a0h = *(const short8*)&lh[m][k0];
        short8 a0l = *(const short8*)&ll[m][k0];
        short8 a1h = *(const short8*)&lh[16 + m][k0];
        short8 a1l = *(const short8*)&ll[16 + m][k0];
        short8 bh = *(const short8*)(WThi + (size_t)(ct * 16 + m) * HH + k0);
        short8 bl = *(const short8*)(WTlo + (size_t)(ct * 16 + m) * HH + k0);
        acc[0] = __builtin_amdgcn_mfma_f32_16x16x32_bf16(a0h, bh, acc[0], 0, 0, 0);
        acc[0] = __builtin_amdgcn_mfma_f32_16x16x32_bf16(a0l, bh, acc[0], 0, 0, 0);
        acc[0] = __builtin_amdgcn_mfma_f32_16x16x32_bf16(a0h, bl, acc[0], 0, 0, 0);
        acc[1] = __builtin_amdgcn_mfma_f32_16x16x32_bf16(a1h, bh, acc[1], 0, 0, 0);
        acc[1] = __builtin_amdgcn_mfma_f32_16x16x32_bf16(a1l, bh, acc[1], 0, 0, 0);
        acc[1] = __builtin_amdgcn_mfma_f32_16x16x32_bf16(a1h, bl, acc[1], 0, 0, 0);
    }
    int colx = ct * 16 + m;
#pragma unroll
    for (int rt = 0; rt < 2; ++rt) {
        int r0 = nodebase + rt * 16 + quad * 4;
#pragma unroll
        for (int reg = 0; reg < 4; ++reg)
            hw_out[(size_t)(r0 + reg) * HH + colx] = __float2half(acc[rt][reg]);
    }
}

// ---------------- Fused: last aggregate (bias only) + per-graph pooling partials ----------------
__global__ __launch_bounds__(512) void agg_pool_kernel(const __half* __restrict__ hw_in,
    const int* __restrict__ row_ptr, const int2* __restrict__ col,
    const float* __restrict__ dinv, const float* __restrict__ bias,
    const int* __restrict__ batch, float* __restrict__ pooled) {
    __shared__ __align__(16) float lf[32][132];
    __shared__ int bg[32];
    int wave = threadIdx.x >> 6;
    int lane = threadIdx.x & 63;
    int grp = lane >> 4;
    int c4 = lane & 15;
    int nodebase = blockIdx.x * 32;
    const uint4* hw4 = (const uint4*)hw_in;

    for (int nn = 0; nn < 4; ++nn) {
        int v = nodebase + wave * 4 + nn;
        int start = row_ptr[v], end = row_ptr[v + 1];
        float a[8] = {}, b[8] = {};
        for (int j0 = start; j0 < end; j0 += 64) {
            int jj = j0 + lane;
            int sp = 0; float np = 0.f;
            if (jj < end) {
                unsigned long long w = __builtin_nontemporal_load((const unsigned long long*)&col[jj]);
                sp = (int)(unsigned)(w & 0xffffffffu);
                np = __int_as_float((int)(unsigned)(w >> 32));
            }
            int rem = min(64, end - j0);
            int iters = (rem + 3) >> 2;
            int it = 0;
            for (; it + 4 <= iters; it += 4) {
                int i0 = it * 4 + grp;
                int s0 = __shfl(sp, i0),      s1 = __shfl(sp, i0 + 4);
                int s2 = __shfl(sp, i0 + 8),  s3 = __shfl(sp, i0 + 12);
                float n0 = __shfl(np, i0),     n1 = __shfl(np, i0 + 4);
                float n2 = __shfl(np, i0 + 8), n3 = __shfl(np, i0 + 12);
                uint4 r0 = hw4[(size_t)s0 * 16 + c4];
                uint4 r1 = hw4[(size_t)s1 * 16 + c4];
                uint4 r2 = hw4[(size_t)s2 * 16 + c4];
                uint4 r3 = hw4[(size_t)s3 * 16 + c4];
                mix8(a, r0, n0);
                mix8(b, r1, n1);
                mix8(a, r2, n2);
                mix8(b, r3, n3);
            }
            for (; it + 2 <= iters; it += 2) {
                int i0 = it * 4 + grp, i1 = i0 + 4;
                int s0 = __shfl(sp, i0), s1 = __shfl(sp, i1);
                float n0 = __shfl(np, i0), n1 = __shfl(np, i1);
                uint4 r0 = hw4[(size_t)s0 * 16 + c4];
                uint4 r1 = hw4[(size_t)s1 * 16 + c4];
                mix8(a, r0, n0);
                mix8(b, r1, n1);
            }
            if (it < iters) {
                int i0 = it * 4 + grp;
                int s0 = __shfl(sp, i0);
                float n0 = __shfl(np, i0);
                uint4 r0 = hw4[(size_t)s0 * 16 + c4];
                mix8(a, r0, n0);
            }
        }
#pragma unroll
        for (int i = 0; i < 8; ++i) a[i] += b[i];
#pragma unroll
        for (int mlt = 16; mlt <= 32; mlt <<= 1) {
#pragma unroll
            for (int i = 0; i < 8; ++i) a[i] += __shfl_xor(a[i], mlt);
        }
        if (grp == 0) {
            int ch = c4 * 8;
            float dv = dinv[v];
            float ns = dv * dv;
            uint4 r = hw4[(size_t)v * 16 + c4];
            mix8(a, r, ns);
            int rloc = wave * 4 + nn;
#pragma unroll
            for (int i = 0; i < 8; ++i) lf[rloc][ch + i] = a[i] + bias[ch + i];
            if (c4 == 0) bg[rloc] = batch[v];
        }
    }
    __syncthreads();
    // pooling partials: 512 threads = 128 ch x 4 row-groups of 8
    int c = threadIdx.x & 127;
    int rh = threadIdx.x >> 7;       // 0..3
    int r0 = rh * 8;
    int curg = bg[r0];
    float run = 0.f;
    for (int r = r0; r < r0 + 8; ++r) {
        int gg = bg[r];
        if (gg != curg) {
            atomicAdd(&pooled[(size_t)curg * HH + c], run);
            run = 0.f; curg = gg;
        }
        run += lf[r][c];
    }
    atomicAdd(&pooled[(size_t)curg * HH + c], run);
}

// ---------------- mean + classifier ----------------
__global__ __launch_bounds__(128) void clf_kernel(const float* __restrict__ pooled,
    const int* __restrict__ batch, const float* __restrict__ Wc,
    const float* __restrict__ bc, float* __restrict__ out) {
    __shared__ float pl[HH];
    int g = blockIdx.x;
    int tid = threadIdx.x;
    int lo = 0, hi = NN;
    while (lo < hi) { int mid = (lo + hi) >> 1; if (batch[mid] < g) lo = mid + 1; else hi = mid; }
    int start = lo;
    lo = 0; hi = NN;
    int g1 = g + 1;
    while (lo < hi) { int mid = (lo + hi) >> 1; if (batch[mid] < g1) lo = mid + 1; else hi = mid; }
    float cnt = (float)(lo - start);
    pl[tid] = pooled[(size_t)g * HH + tid] / fmaxf(cnt, 1.0f);
    __syncthreads();
    if (tid < OUTD) {
        float acc = bc[tid];
#pragma unroll 16
        for (int c = 0; c < HH; ++c) acc += pl[c] * Wc[c * OUTD + tid];
        out[g * OUTD + tid] = acc;
    }
}

extern "C" void kernel_launch(void* const* d_in, const int* in_sizes, int n_in,
                              void* d_out, int out_size, void* d_ws, size_t ws_size,
                              hipStream_t stream) {
    const int*   x      = (const int*)d_in[0];
    const int*   eidx   = (const int*)d_in[1];
    const int*   batch  = (const int*)d_in[2];
    const float* emb    = (const float*)d_in[3];
    const float* Ws     = (const float*)d_in[4];
    const float* bs     = (const float*)d_in[5];
    const float* gamma  = (const float*)d_in[6];
    const float* beta   = (const float*)d_in[7];
    const float* rmean  = (const float*)d_in[8];
    const float* rvar   = (const float*)d_in[9];
    const float* Wclf   = (const float*)d_in[10];
    const float* bclf   = (const float*)d_in[11];
    float* out = (float*)d_out;

    const int* e_src = eidx;
    const int* e_dst = eidx + EE;

    char* ws = (char*)d_ws;
    size_t off = 0;
    auto take = [&](size_t bytes) -> void* {
        void* p = ws + off;
        off = (off + bytes + 255) & ~(size_t)255;
        return p;
    };
    float* dinv     = (float*)take((size_t)NN * 4);
    int*   cnt      = (int*)  take((size_t)NN * 4);
    int*   row_ptr  = (int*)  take((size_t)(NN + 1) * 4);
    int*   bsum     = (int*)  take((size_t)NB_SCAN * 4);
    int*   bcur     = (int*)  take((size_t)256 * 4);
    int*   bucket_edges = (int*)take((size_t)NBUCK * BCAP * 4);
    int2*  col      = (int2*) take((size_t)EE * 8);
    __half* hwA     = (__half*)take((size_t)NN * HH * 2);
    __half* hwB     = (__half*)take((size_t)NN * HH * 2);
    float* pooled   = (float*)take((size_t)GG * HH * 4);
    unsigned short* WThi = (unsigned short*)take((size_t)LL * HH * HH * 2);
    unsigned short* WTlo = (unsigned short*)take((size_t)LL * HH * HH * 2);

    hipMemsetAsync(bcur, 0, 256 * 4, stream);
    hipMemsetAsync(pooled, 0, (size_t)GG * HH * 4, stream);

    split_kernel<<<(EE + CHUNK - 1) / CHUNK, 256, 0, stream>>>(e_src, e_dst, bcur, bucket_edges);
    bhist_kernel<<<NBUCK, 256, 0, stream>>>(bcur, bucket_edges, cnt);
    scanA_kernel<<<NB_SCAN, 256, 0, stream>>>(cnt, bsum, dinv);
    scanB_kernel<<<1, 128, 0, stream>>>(bsum);
    scanC_kernel<<<NB_SCAN, 256, 0, stream>>>(cnt, bsum, row_ptr);
    cscatter_kernel<<<NBUCK, 256, 0, stream>>>(bcur, bucket_edges, row_ptr, dinv, col);
    wconv_kernel<<<(LL * HH * HH + 255) / 256, 256, 0, stream>>>(Ws, WThi, WTlo);

    // encoder -> LDS -> @ W0 -> hw1
    enc_mm_kernel<<<NN / 32, 256, 0, stream>>>(x, emb, WThi, WTlo, hwA);
    // layer 0: agg(hw1)+bias0+BN0+ReLU -> LDS -> @ W1 -> hw2
    agg_mm_kernel<<<NN / 32, 512, 0, stream>>>(hwA, row_ptr, col, dinv,
        bs, gamma, beta, rmean, rvar,
        WThi + (size_t)1 * HH * HH, WTlo + (size_t)1 * HH * HH, hwB);
    // layer 1: agg(hw2)+bias1+BN1+ReLU -> LDS -> @ W2 -> hw3
    agg_mm_kernel<<<NN / 32, 512, 0, stream>>>(hwB, row_ptr, col, dinv,
        bs + HH, gamma + HH, beta + HH, rmean + HH, rvar + HH,
        WThi + (size_t)2 * HH * HH, WTlo + (size_t)2 * HH * HH, hwA);
    // layer 2: agg(hw3)+bias2 -> pooling partials
    agg_pool_kernel<<<NN / 32, 512, 0, stream>>>(hwA, row_ptr, col, dinv,
        bs + 2 * HH, batch, pooled);

    clf_kernel<<<GG, 128, 0, stream>>>(pooled, batch, Wclf, bclf, out);
}